// Round 1
// baseline (448.635 us; speedup 1.0000x reference)
//
#include <hip/hip_runtime.h>

// Block_58394375356873: HomoAttention transformer block, MI355X gfx950.
// I/O dtype: float32 (per reference). Internal GEMM compute: bf16 MFMA.
// M = B*N = 64*196 = 12544.
//
// R1: big GEMMs (qk, fc1, fc2) moved to gemm8p: 256x256 tile, BK=64, 512 thr
// (8 waves 2Mx4N), 128KiB LDS dbuf, 4 phases/K-tile with counted vmcnt(2)
// (never 0 in main loop), setprio(1) around MFMA clusters (T3+T4+T5).

#define BATCH 64
#define SEQ   196
#define CH    768
#define NHEAD 12
#define HDIM  64
#define TOPK  16
#define HID   3072
#define MROWS 12544
#define MHALF 6272
#define SCALE_F 0.125f  // 64^-0.5
#define NEGBIG -3e38f

typedef __bf16 bf16x8 __attribute__((ext_vector_type(8)));
typedef float  f32x4  __attribute__((ext_vector_type(4)));

__device__ __forceinline__ unsigned short f2b(float f) {
    union { float f; unsigned int i; } c; c.f = f;
    unsigned int u = c.i;
    return (unsigned short)((u + 0x7fffu + ((u >> 16) & 1u)) >> 16); // RNE
}
__device__ __forceinline__ float b2f(unsigned short u) {
    union { unsigned int i; float f; } c; c.i = ((unsigned int)u) << 16; return c.f;
}

// tanh-form GELU, |err vs exact erf-GELU| < 4e-4, ~10 VALU ops.
__device__ __forceinline__ float gelu_f(float v) {
    float u = v * (0.7978845608f + 0.0356774081f * v * v);
    float e = __expf(2.0f * u);
    float th = 1.0f - 2.0f / (e + 1.0f);
    return 0.5f * v * (1.0f + th);
}

// async global->LDS, 16B per lane. LDS base must be wave-uniform; HW adds lane*16.
__device__ __forceinline__ void async16(const unsigned short* g, unsigned short* l) {
    __builtin_amdgcn_global_load_lds(
        (const __attribute__((address_space(1))) unsigned int*)(g),
        (__attribute__((address_space(3))) unsigned int*)(l), 16, 0, 0);
}

// ---------------- all-weights f32 -> bf16, one dispatch ----------------
__global__ __launch_bounds__(256) void f2b4_k(const float* __restrict__ s0, unsigned short* __restrict__ d0, int n0,
                                              const float* __restrict__ s1, unsigned short* __restrict__ d1, int n1,
                                              const float* __restrict__ s2, unsigned short* __restrict__ d2, int n2,
                                              const float* __restrict__ s3, unsigned short* __restrict__ d3, int n3)
{
    int idx = (blockIdx.x * 256 + threadIdx.x) * 4;
    const float* s; unsigned short* d; int n;
    if (idx < n0) { s = s0; d = d0; n = n0; }
    else {
        idx -= n0;
        if (idx < n1) { s = s1; d = d1; n = n1; }
        else {
            idx -= n1;
            if (idx < n2) { s = s2; d = d2; n = n2; }
            else { idx -= n2; s = s3; d = d3; n = n3; }
        }
    }
    if (idx < n) {
        float4 v = *(const float4*)(s + idx);
        ushort4 o;
        o.x = f2b(v.x); o.y = f2b(v.y); o.z = f2b(v.z); o.w = f2b(v.w);
        *(ushort4*)(d + idx) = o;
    }
}

// ---------------- LayerNorm: f32|bf16 in -> bf16 out, one block per row ----------------
template<bool INF32>
__global__ __launch_bounds__(256) void ln_k(const void* __restrict__ xin,
                                            const float* __restrict__ gw,
                                            const float* __restrict__ bw,
                                            unsigned short* __restrict__ out)
{
    const int row = blockIdx.x;
    const int tid = threadIdx.x;
    float v0, v1, v2;
    if constexpr (INF32) {
        const float* xr = (const float*)xin + (size_t)row * CH;
        v0 = xr[tid]; v1 = xr[tid + 256]; v2 = xr[tid + 512];
    } else {
        const unsigned short* xr = (const unsigned short*)xin + (size_t)row * CH;
        v0 = b2f(xr[tid]); v1 = b2f(xr[tid + 256]); v2 = b2f(xr[tid + 512]);
    }
    float s  = v0 + v1 + v2;
    float sq = v0*v0 + v1*v1 + v2*v2;
#pragma unroll
    for (int off = 32; off > 0; off >>= 1) {
        s  += __shfl_down(s, off, 64);
        sq += __shfl_down(sq, off, 64);
    }
    __shared__ __align__(16) float red[8];
    if ((tid & 63) == 0) { red[(tid >> 6) * 2] = s; red[(tid >> 6) * 2 + 1] = sq; }
    __syncthreads();
    s  = red[0] + red[2] + red[4] + red[6];
    sq = red[1] + red[3] + red[5] + red[7];
    float mu  = s * (1.0f / CH);
    float var = sq * (1.0f / CH) - mu * mu;
    float rs  = rsqrtf(var + 1e-5f);
    unsigned short* orow = out + (size_t)row * CH;
    orow[tid]       = f2b((v0 - mu) * rs * gw[tid]       + bw[tid]);
    orow[tid + 256] = f2b((v1 - mu) * rs * gw[tid + 256] + bw[tid + 256]);
    orow[tid + 512] = f2b((v2 - mu) * rs * gw[tid + 512] + bw[tid + 512]);
}

// ---------------- NT GEMM (legacy 2-barrier): C = A @ W^T (+bias)(+gelu)(+resid) ----
// Kept for attn-proj (K=192) and halved fallback paths (M=6272 not /256).
template<int TM, int TN, bool BIAS, int RES, bool GELU, bool OUTF>
__global__ __launch_bounds__(256, 4)
void gemm_bt(const unsigned short* __restrict__ A,
             const unsigned short* __restrict__ Bw,
             const float* __restrict__ bias,
             const void* __restrict__ resid,
             void* __restrict__ Cout,
             int M, int N, int K)
{
    constexpr int WROWS = (TM == 128) ? 2 : 1;
    constexpr int WCOLS = 4 / WROWS;
    constexpr int JF = TN / (16 * WCOLS);           // frag cols per wave
    __shared__ __align__(16) unsigned short As[2][TM * 32];
    __shared__ __align__(16) unsigned short Bs[2][TN * 32];
    const int tid  = threadIdx.x;
    const int w    = tid >> 6;
    const int lane = tid & 63;

    const int gridN = gridDim.x, gridM = gridDim.y;
    const int lid = blockIdx.y * gridN + blockIdx.x;
    const int SG = 8 * gridN;
    const int sg = lid / SG, r = lid % SG;
    const int remM = gridM - sg * 8;
    int mloc, nloc;
    if (remM >= 8) { mloc = sg * 8 + (r & 7); nloc = r >> 3; }
    else           { mloc = sg * 8 + r % remM; nloc = r / remM; }
    const int tileM = mloc * TM;
    const int tileN = nloc * TN;

    const int wm = (w / WCOLS) * 64;                // TM=64 -> 0
    const int wn = (w % WCOLS) * (JF * 16);
    const int q   = lane >> 4;
    const int l16 = lane & 15;
    const int csw = (q ^ (l16 & 3)) * 8;            // swizzled chunk offset for frag reads

    f32x4 acc[4][JF];
#pragma unroll
    for (int i = 0; i < 4; ++i)
#pragma unroll
        for (int j = 0; j < JF; ++j) acc[i][j] = (f32x4){0.f, 0.f, 0.f, 0.f};

    const int r0 = tid >> 2;
    const int g0 = ((tid & 3) ^ (r0 & 3)) * 8;

    const unsigned short* pB[TN / 64];
    const unsigned short* pA[TM / 64];
#pragma unroll
    for (int c = 0; c < TN / 64; ++c) pB[c] = Bw + (size_t)(tileN + r0 + c * 64) * K + g0;
#pragma unroll
    for (int c = 0; c < TM / 64; ++c) pA[c] = A + (size_t)(tileM + r0 + c * 64) * K + g0;

    auto stage = [&](int buf) {
#pragma unroll
        for (int c = 0; c < TN / 64; ++c) {
            async16(pB[c], &Bs[buf][(size_t)(c * 256 + w * 64) * 8]);
            pB[c] += 32;
        }
#pragma unroll
        for (int c = 0; c < TM / 64; ++c) {
            async16(pA[c], &As[buf][(size_t)(c * 256 + w * 64) * 8]);
            pA[c] += 32;
        }
    };

    const int kIters = K >> 5;
    stage(0);
    int cur = 0;
    for (int kt = 0; kt < kIters; ++kt) {
        __syncthreads();
        if (kt + 1 < kIters) stage(cur ^ 1);
        bf16x8 af[4], bfr[JF];
#pragma unroll
        for (int i = 0; i < 4; ++i)
            af[i] = *(const bf16x8*)&As[cur][(wm + i * 16 + l16) * 32 + csw];
#pragma unroll
        for (int j = 0; j < JF; ++j)
            bfr[j] = *(const bf16x8*)&Bs[cur][(wn + j * 16 + l16) * 32 + csw];
#pragma unroll
        for (int i = 0; i < 4; ++i)
#pragma unroll
            for (int j = 0; j < JF; ++j)
                acc[i][j] = __builtin_amdgcn_mfma_f32_16x16x32_bf16(af[i], bfr[j], acc[i][j], 0, 0, 0);
        cur ^= 1;
    }

#pragma unroll
    for (int i = 0; i < 4; ++i) {
#pragma unroll
        for (int r2 = 0; r2 < 4; ++r2) {
            int row = tileM + wm + i * 16 + q * 4 + r2;
#pragma unroll
            for (int j = 0; j < JF; ++j) {
                int col = tileN + wn + j * 16 + l16;
                float v = acc[i][j][r2];
                if (BIAS) v += bias[col];
                if (GELU) v = gelu_f(v);
                if (RES == 1) v += ((const float*)resid)[(size_t)row * N + col];
                if (RES == 2) v += b2f(((const unsigned short*)resid)[(size_t)row * N + col]);
                if (OUTF) ((float*)Cout)[(size_t)row * N + col] = v;
                else      ((unsigned short*)Cout)[(size_t)row * N + col] = f2b(v);
            }
        }
    }
}

// ---------------- 8-phase 256x256 NT GEMM (T3+T4+T5) ----------------
// C[M,N] = A[M,KC] @ W[N,KC]^T (+bias)(+gelu)(+resid). M,N % 256 == 0, KC % 64 == 0.
// 512 threads = 8 waves (2M x 4N); per-wave 128x64 output = acc[8][4] f32x4.
// LDS: 2 dbuf x 256x64 bf16 for A and B = 128 KiB (1 block/CU).
// K-tile (BK=64) = 4 phases = C-quadrants (0,0),(0,1),(1,1),(1,0); 16 MFMA each.
// LDS swizzle: 16B chunk slot = chunk ^ (row&7) (conflict-free: 2 lanes/slot),
// applied by pre-swizzling the global source (global_load_lds dest is linear).
// Staging ring: half-tiles (A.h0,A.h1,B.h0,B.h1 = 16KB each, 2 loads/wave):
//   tile u phases 0..2 stage (u+1).{A1,B0,B1}; phase 3 stages (u+2).A0.
//   WAR-safe: all ds_reads of a buffer are issued by its phase 2 (and drained
//   by that phase's lgkmcnt(0)+barrier); phase-3 stage targets the current
//   buffer only after that point. Counted vmcnt(2) at each tile boundary
//   (the 2 newest loads = (u+2).A0 may stay in flight); vmcnt(0) only at the
//   last boundary. No __syncthreads in the loop -> no full drain.
template<int KC, bool BIAS, int RES, bool GELU, bool OUTF>
__global__ __launch_bounds__(512, 2)
void gemm8p(const unsigned short* __restrict__ A,
            const unsigned short* __restrict__ Bw,
            const float* __restrict__ bias,
            const void* __restrict__ resid,
            void* __restrict__ Cout,
            int M, int N)
{
    constexpr int T = KC / 64;
    __shared__ __align__(16) unsigned short As[2][256 * 64];
    __shared__ __align__(16) unsigned short Bs[2][256 * 64];
    const int tid  = threadIdx.x;
    const int w    = tid >> 6;
    const int lane = tid & 63;
    const int q    = lane >> 4;
    const int l16  = lane & 15;

    // XCD-locality remap: 8 M-stripes per supergroup; same-stripe blocks share XCD.
    const int gridN = gridDim.x, gridM = gridDim.y;
    const int lid = blockIdx.y * gridN + blockIdx.x;
    const int SG = 8 * gridN;
    const int sg = lid / SG, rr = lid % SG;
    const int remM = gridM - sg * 8;
    int mloc, nloc;
    if (remM >= 8) { mloc = sg * 8 + (rr & 7); nloc = rr >> 3; }
    else           { mloc = sg * 8 + rr % remM; nloc = rr / remM; }
    const int tileM = mloc * 256, tileN = nloc * 256;

    const int wm = (w >> 2) * 128;   // wave row offset (2 rows of waves)
    const int wn = (w & 3) * 64;     // wave col offset (4 cols of waves)

    // staging source (pre-swizzled): thread t covers LDS chunk t (call0) / t+512 (call1)
    const int r0 = tid >> 3;                  // row 0..63 within half-tile call
    const int g0 = (tid & 7) ^ (r0 & 7);      // global chunk held at this LDS slot
    const unsigned short* pA0 = A  + (size_t)(tileM + r0) * KC + g0 * 8;
    const unsigned short* pB0 = Bw + (size_t)(tileN + r0) * KC + g0 * 8;

    auto stageHT = [&](int v, int j) {        // j: 0=A.h0 1=A.h1 2=B.h0 3=B.h1
        const unsigned short* src = (j < 2 ? pA0 : pB0)
                                  + (size_t)(j & 1) * 128 * KC + (size_t)v * 64;
        unsigned short* dst = (j < 2 ? As[v & 1] : Bs[v & 1]) + (j & 1) * 8192 + w * 512;
        async16(src, dst);
        async16(src + (size_t)64 * KC, dst + 4096);
    };

    f32x4 acc[8][4];
#pragma unroll
    for (int i = 0; i < 8; ++i)
#pragma unroll
        for (int jn = 0; jn < 4; ++jn) acc[i][jn] = (f32x4){0.f, 0.f, 0.f, 0.f};

    // prologue: tile0 fully + tile1.A0; allow tile1.A0 (2 loads) to stay in flight
    stageHT(0, 0); stageHT(0, 1); stageHT(0, 2); stageHT(0, 3); stageHT(1, 0);
    asm volatile("s_waitcnt vmcnt(2)" ::: "memory");
    __builtin_amdgcn_s_barrier();

    const int arow = wm + l16;
    const int brow = wn + l16;
    const int xsw  = l16 & 7;

#pragma unroll 2
    for (int u = 0; u < T; ++u) {
        const unsigned short* Ab = As[u & 1];
        const unsigned short* Bb = Bs[u & 1];
        bf16x8 af[4][2], b0[2][2], b1[2][2];

        // ---------- phase 0: quadrant (mh0, nh0) : 12 ds_read ----------
#pragma unroll
        for (int m = 0; m < 4; ++m)
#pragma unroll
            for (int kk = 0; kk < 2; ++kk)
                af[m][kk] = *(const bf16x8*)&Ab[(arow + m * 16) * 64 + ((((kk << 2) | q) ^ xsw) << 3)];
#pragma unroll
        for (int n = 0; n < 2; ++n)
#pragma unroll
            for (int kk = 0; kk < 2; ++kk)
                b0[n][kk] = *(const bf16x8*)&Bb[(brow + n * 16) * 64 + ((((kk << 2) | q) ^ xsw) << 3)];
        if (u + 1 < T) stageHT(u + 1, 1);
        __builtin_amdgcn_s_barrier();
        asm volatile("s_waitcnt lgkmcnt(0)" ::: "memory");
        __builtin_amdgcn_sched_barrier(0);
        __builtin_amdgcn_s_setprio(1);
#pragma unroll
        for (int kk = 0; kk < 2; ++kk)
#pragma unroll
            for (int m = 0; m < 4; ++m)
#pragma unroll
                for (int n = 0; n < 2; ++n)
                    acc[m][n] = __builtin_amdgcn_mfma_f32_16x16x32_bf16(af[m][kk], b0[n][kk], acc[m][n], 0, 0, 0);
        __builtin_amdgcn_s_setprio(0);
        __builtin_amdgcn_s_barrier();

        // ---------- phase 1: quadrant (mh0, nh1) : 4 ds_read ----------
#pragma unroll
        for (int n = 0; n < 2; ++n)
#pragma unroll
            for (int kk = 0; kk < 2; ++kk)
                b1[n][kk] = *(const bf16x8*)&Bb[(brow + 32 + n * 16) * 64 + ((((kk << 2) | q) ^ xsw) << 3)];
        if (u + 1 < T) stageHT(u + 1, 2);
        __builtin_amdgcn_s_barrier();
        asm volatile("s_waitcnt lgkmcnt(0)" ::: "memory");
        __builtin_amdgcn_sched_barrier(0);
        __builtin_amdgcn_s_setprio(1);
#pragma unroll
        for (int kk = 0; kk < 2; ++kk)
#pragma unroll
            for (int m = 0; m < 4; ++m)
#pragma unroll
                for (int n = 0; n < 2; ++n)
                    acc[m][2 + n] = __builtin_amdgcn_mfma_f32_16x16x32_bf16(af[m][kk], b1[n][kk], acc[m][2 + n], 0, 0, 0);
        __builtin_amdgcn_s_setprio(0);
        __builtin_amdgcn_s_barrier();

        // ---------- phase 2: quadrant (mh1, nh1) : 8 ds_read (last reads of buf) ----------
#pragma unroll
        for (int m = 0; m < 4; ++m)
#pragma unroll
            for (int kk = 0; kk < 2; ++kk)
                af[m][kk] = *(const bf16x8*)&Ab[(arow + 64 + m * 16) * 64 + ((((kk << 2) | q) ^ xsw) << 3)];
        if (u + 1 < T) stageHT(u + 1, 3);
        __builtin_amdgcn_s_barrier();
        asm volatile("s_waitcnt lgkmcnt(0)" ::: "memory");
        __builtin_amdgcn_sched_barrier(0);
        __builtin_amdgcn_s_setprio(1);
#pragma unroll
        for (int kk = 0; kk < 2; ++kk)
#pragma unroll
            for (int m = 0; m < 4; ++m)
#pragma unroll
                for (int n = 0; n < 2; ++n)
                    acc[4 + m][2 + n] = __builtin_amdgcn_mfma_f32_16x16x32_bf16(af[m][kk], b1[n][kk], acc[4 + m][2 + n], 0, 0, 0);
        __builtin_amdgcn_s_setprio(0);
        __builtin_amdgcn_s_barrier();

        // ---------- phase 3: quadrant (mh1, nh0) : 0 ds_read; boundary vmcnt ----------
        if (u + 2 < T) {
            stageHT(u + 2, 0);                       // into current buf (all reads done)
            asm volatile("s_waitcnt vmcnt(2)" ::: "memory");  // keep (u+2).A0 in flight
        } else if (u + 1 < T) {
            asm volatile("s_waitcnt vmcnt(0)" ::: "memory");  // last boundary: full drain
        }
        __builtin_amdgcn_s_barrier();
        __builtin_amdgcn_s_setprio(1);
#pragma unroll
        for (int kk = 0; kk < 2; ++kk)
#pragma unroll
            for (int m = 0; m < 4; ++m)
#pragma unroll
                for (int n = 0; n < 2; ++n)
                    acc[4 + m][n] = __builtin_amdgcn_mfma_f32_16x16x32_bf16(af[m][kk], b0[n][kk], acc[4 + m][n], 0, 0, 0);
        __builtin_amdgcn_s_setprio(0);
        __builtin_amdgcn_s_barrier();
    }

    // ---------------- epilogue ----------------
#pragma unroll
    for (int mh = 0; mh < 2; ++mh)
#pragma unroll
        for (int m = 0; m < 4; ++m)
#pragma unroll
            for (int r2 = 0; r2 < 4; ++r2) {
                const int row = tileM + wm + mh * 64 + m * 16 + q * 4 + r2;
#pragma unroll
                for (int nh = 0; nh < 2; ++nh)
#pragma unroll
                    for (int n = 0; n < 2; ++n) {
                        const int col = tileN + wn + nh * 32 + n * 16 + l16;
                        float v = acc[mh * 4 + m][nh * 2 + n][r2];
                        if (BIAS) v += bias[col];
                        if (GELU) v = gelu_f(v);
                        if (RES == 1) v += ((const float*)resid)[(size_t)row * N + col];
                        if (RES == 2) v += b2f(((const unsigned short*)resid)[(size_t)row * N + col]);
                        if (OUTF) ((float*)Cout)[(size_t)row * N + col] = v;
                        else      ((unsigned short*)Cout)[(size_t)row * N + col] = f2b(v);
                    }
            }
    (void)M;
}

// ---------------- Attention: MFMA scores + in-register top-16 + softmax ----------------
__global__ __launch_bounds__(256) void attn_topk(const unsigned short* __restrict__ qk,
                                                 unsigned short* __restrict__ aout)
{
    const int bh = blockIdx.x;
    const int b = bh / NHEAD, h = bh % NHEAD;
    __shared__ __align__(16) unsigned short Qs[208 * 64];
    __shared__ __align__(16) unsigned short Ks[208 * 64];
    const int tid = threadIdx.x;

    for (int i = tid; i < 208 * 8; i += 256) {
        int row = i >> 3, c = i & 7;
        uint4 vq = make_uint4(0, 0, 0, 0), vk = vq;
        if (row < SEQ) {
            const uint4* gp = (const uint4*)(qk + ((size_t)(b * SEQ + row) * 1536 + h * 64));
            vq = gp[c];        // q half
            vk = gp[c + 96];   // k half: +768 shorts = +96 uint4
        }
        int slot = c ^ (row & 7);
        *(uint4*)&Qs[row * 64 + slot * 8] = vq;
        *(uint4*)&Ks[row * 64 + slot * 8] = vk;
    }
    __syncthreads();

    const int w = tid >> 6, lane = tid & 63;
    const int q = lane >> 4, l16 = lane & 15;

    for (int tn = w; tn < 13; tn += 4) {
        const int nrow = tn * 16 + l16;
        const int nsw = nrow & 7;
        bf16x8 bq0 = *(const bf16x8*)&Qs[nrow * 64 + ((0 * 4 + q) ^ nsw) * 8];
        bf16x8 bq1 = *(const bf16x8*)&Qs[nrow * 64 + ((1 * 4 + q) ^ nsw) * 8];

        float t[TOPK];
#pragma unroll
        for (int j = 0; j < TOPK; ++j) t[j] = NEGBIG;

        for (int tm = 0; tm < 12; ++tm) {
            const int mrow = tm * 16 + l16;
            const int msw = mrow & 7;
            bf16x8 ak0 = *(const bf16x8*)&Ks[mrow * 64 + ((0 * 4 + q) ^ msw) * 8];
            bf16x8 ak1 = *(const bf16x8*)&Ks[mrow * 64 + ((1 * 4 + q) ^ msw) * 8];
            f32x4 acc = (f32x4){0.f, 0.f, 0.f, 0.f};
            acc = __builtin_amdgcn_mfma_f32_16x16x32_bf16(ak0, bq0, acc, 0, 0, 0);
            acc = __builtin_amdgcn_mfma_f32_16x16x32_bf16(ak1, bq1, acc, 0, 0, 0);
#pragma unroll
            for (int r = 0; r < 4; ++r) {
                float v = acc[r];
#pragma unroll
                for (int j = 0; j < TOPK; ++j) {
                    float mx = fmaxf(t[j], v);
                    v = fminf(t[j], v);
                    t[j] = mx;
                }
            }
        }
        {   // m-tile 12: m = 192 + q*4 + r valid only for q==0
            const int mrow = 12 * 16 + l16;
            const int msw = mrow & 7;
            bf16x8 ak0 = *(const bf16x8*)&Ks[mrow * 64 + ((0 * 4 + q) ^ msw) * 8];
            bf16x8 ak1 = *(const bf16x8*)&Ks[mrow * 64 + ((1 * 4 + q) ^ msw) * 8];
            f32x4 acc = (f32x4){0.f, 0.f, 0.f, 0.f};
            acc = __builtin_amdgcn_mfma_f32_16x16x32_bf16(ak0, bq0, acc, 0, 0, 0);
            acc = __builtin_amdgcn_mfma_f32_16x16x32_bf16(ak1, bq1, acc, 0, 0, 0);
#pragma unroll
            for (int r = 0; r < 4; ++r) {
                float v = (q == 0) ? acc[r] : NEGBIG;
#pragma unroll
                for (int j = 0; j < TOPK; ++j) {
                    float mx = fmaxf(t[j], v);
                    v = fminf(t[j], v);
                    t[j] = mx;
                }
            }
        }

#pragma unroll
        for (int stage = 0; stage < 2; ++stage) {
            const int xm = 16 << stage;
            float bl[TOPK], c[TOPK];
#pragma unroll
            for (int j = 0; j < TOPK; ++j) bl[j] = __shfl_xor(t[j], xm, 64);
#pragma unroll
            for (int j = 0; j < TOPK; ++j) c[j] = fmaxf(t[j], bl[TOPK - 1 - j]);
#pragma unroll
            for (int s = 8; s >= 1; s >>= 1) {
#pragma unroll
                for (int i = 0; i < TOPK; ++i) {
                    if ((i & s) == 0) {
                        float mx = fmaxf(c[i], c[i + s]);
                        c[i + s] = fminf(c[i], c[i + s]);
                        c[i] = mx;
                    }
                }
            }
#pragma unroll
            for (int j = 0; j < TOPK; ++j) t[j] = c[j];
        }

        if (q == 0 && nrow < SEQ) {
            float e[TOPK], sum = 0.f;
#pragma unroll
            for (int j = 0; j < TOPK; ++j) { e[j] = __expf((t[j] - t[0]) * SCALE_F); sum += e[j]; }
            float inv = 1.0f / sum;
            unsigned int pk[8];
#pragma unroll
            for (int jj = 0; jj < 8; ++jj)
                pk[jj] = (unsigned int)f2b(e[2 * jj] * inv) |
                         ((unsigned int)f2b(e[2 * jj + 1] * inv) << 16);
            unsigned short* dst = aout + ((size_t)(b * SEQ + nrow)) * (NHEAD * TOPK) + h * TOPK;
            ((uint4*)dst)[0] = make_uint4(pk[0], pk[1], pk[2], pk[3]);
            ((uint4*)dst)[1] = make_uint4(pk[4], pk[5], pk[6], pk[7]);
        }
    }
}

// ---------------- Launch ----------------
extern "C" void kernel_launch(void* const* d_in, const int* in_sizes, int n_in,
                              void* d_out, int out_size, void* d_ws, size_t ws_size,
                              hipStream_t stream)
{
    const float* x    = (const float*)d_in[0];
    const float* g1   = (const float*)d_in[1];
    const float* bb1  = (const float*)d_in[2];
    const float* qkw  = (const float*)d_in[3];
    const float* pw   = (const float*)d_in[4];
    const float* pb   = (const float*)d_in[5];
    const float* g2   = (const float*)d_in[6];
    const float* bb2  = (const float*)d_in[7];
    const float* f1w  = (const float*)d_in[8];
    const float* f1b  = (const float*)d_in[9];
    const float* f2w  = (const float*)d_in[10];
    const float* f2bp = (const float*)d_in[11];
    float* out = (float*)d_out;

    // layout: hbuf | weights(wqk,wp,wf1,wf2) | av | qk/gg | x1b
    char* ws = (char*)d_ws;
    const size_t SZ_H   = (size_t)MROWS * CH * 2;              // 19,267,584
    const size_t N_WQK  = (size_t)2 * CH * CH;
    const size_t N_WP   = (size_t)CH * (NHEAD * TOPK);
    const size_t N_WF   = (size_t)HID * CH;
    const size_t SZ_W   = (N_WQK + N_WP + 2 * N_WF) * 2;       // 12,091,392
    const size_t SZ_A   = (size_t)MROWS * (NHEAD * TOPK) * 2;  //  4,816,896
    const size_t SZ_QK  = (size_t)MROWS * 2 * CH * 2;          // 38,535,168
    const size_t SZ_GGF = (size_t)MROWS * HID * 2;             // 77,070,336

    unsigned short* hbuf = (unsigned short*)(ws);
    unsigned short* wqk  = (unsigned short*)(ws + SZ_H);
    unsigned short* wp   = wqk + N_WQK;
    unsigned short* wf1  = wp  + N_WP;
    unsigned short* wf2  = wf1 + N_WF;
    unsigned short* av   = (unsigned short*)(ws + SZ_H + SZ_W);
    unsigned short* qk   = (unsigned short*)(ws + SZ_H + SZ_W + SZ_A);
    unsigned short* gg   = qk;   // overlays qk (dead by MLP time)

    const size_t base = SZ_H + SZ_W + SZ_A;
    const bool fullMLP = ws_size >= base + SZ_GGF + SZ_H;      // 132.5 MB: full-M + bf16 x1
    const bool bx1     = fullMLP || ws_size >= base + SZ_QK + SZ_H;  // 94 MB: halves + bf16 x1
    unsigned short* x1b = (unsigned short*)(ws + base + (fullMLP ? SZ_GGF : SZ_QK));
    float* x1 = out;   // f32 fallback residual lives in d_out

    // 0) all weights f32 -> bf16, one dispatch
    {
        int total4 = (int)((N_WQK + N_WP + 2 * N_WF) / 4);
        f2b4_k<<<(total4 + 255) / 256, 256, 0, stream>>>(
            qkw, wqk, (int)N_WQK, pw, wp, (int)N_WP,
            f1w, wf1, (int)N_WF, f2w, wf2, (int)N_WF);
    }

    // 1) LN1: x(f32) -> h (bf16)
    ln_k<true><<<MROWS, 256, 0, stream>>>(x, g1, bb1, hbuf);
    // 2) qk = h @ qk_w^T   [12544 x 1536], K=768   (8-phase 256^2: grid 6x49)
    gemm8p<CH, false, 0, false, false><<<dim3(2 * CH / 256, MROWS / 256), 512, 0, stream>>>(
        hbuf, wqk, nullptr, nullptr, qk, MROWS, 2 * CH);
    // 3) attention -> top16 softmax weights [12544 x 192] bf16
    attn_topk<<<BATCH * NHEAD, 256, 0, stream>>>(qk, av);

    if (bx1) {
        // 4) x1b = bf16(x + a @ attn_proj_w^T + b)   (64x128: grid 6x196)
        gemm_bt<64, 128, true, 1, false, false><<<dim3(6, 196), 256, 0, stream>>>(
            av, wp, pb, x, x1b, MROWS, CH, NHEAD * TOPK);
        // 5) LN2: x1b (bf16) -> h2
        ln_k<false><<<MROWS, 256, 0, stream>>>(x1b, g2, bb2, hbuf);
        if (fullMLP) {
            // fc1: [12544 x 3072], K=768  (8-phase 256^2: grid 12x49)
            gemm8p<CH, true, 0, true, false><<<dim3(HID / 256, MROWS / 256), 512, 0, stream>>>(
                hbuf, wf1, f1b, nullptr, gg, MROWS, HID);
            // fc2: [12544 x 768], K=3072 (8-phase 256^2: grid 3x49)
            gemm8p<HID, true, 2, false, true><<<dim3(CH / 256, MROWS / 256), 512, 0, stream>>>(
                gg, wf2, f2bp, x1b, out, MROWS, CH);
        } else {
            for (int half = 0; half < 2; ++half) {
                const size_t ro = (size_t)half * MHALF;
                gemm_bt<128, 128, true, 0, true, false><<<dim3(24, 49), 256, 0, stream>>>(
                    hbuf + ro * CH, wf1, f1b, nullptr, gg, MHALF, HID, CH);
                gemm_bt<64, 256, true, 2, false, true><<<dim3(3, 98), 256, 0, stream>>>(
                    gg, wf2, f2bp, x1b + ro * CH, out + ro * CH, MHALF, CH, HID);
            }
        }
    } else {
        // conservative fallback: f32 x1 in d_out, halved MLP (74.7 MB ws)
        gemm_bt<64, 128, true, 1, false, true><<<dim3(6, 196), 256, 0, stream>>>(
            av, wp, pb, x, x1, MROWS, CH, NHEAD * TOPK);
        ln_k<true><<<MROWS, 256, 0, stream>>>(x1, g2, bb2, hbuf);
        for (int half = 0; half < 2; ++half) {
            const size_t ro = (size_t)half * MHALF;
            gemm_bt<128, 128, true, 0, true, false><<<dim3(24, 49), 256, 0, stream>>>(
                hbuf + ro * CH, wf1, f1b, nullptr, gg, MHALF, HID, CH);
            gemm_bt<64, 256, true, 1, false, true><<<dim3(3, 98), 256, 0, stream>>>(
                gg, wf2, f2bp, x1 + ro * CH, out + ro * CH, MHALF, CH, HID);
        }
    }
}

// Round 3
// 436.767 us; speedup vs baseline: 1.0272x; 1.0272x over previous
//
#include <hip/hip_runtime.h>

// Block_58394375356873: HomoAttention transformer block, MI355X gfx950.
// I/O dtype: float32 (per reference). Internal GEMM compute: bf16 MFMA.
// M = B*N = 64*196 = 12544.
//
// R3: gemm8p correctness fix of R2's schedule:
//  (a) staged quarters now match wave reads: A split by row bit6
//      (ph0 reads {0-63,128-191}, ph2 reads {64-127,192-255}), B split by
//      row bit5 (b0: bit5==0, b1: bit5==1). Quarters are 8-row-aligned
//      pieces -> per-wave DMA dst offsets scatter them correctly.
//  (b) every mid-tile vmcnt wait is followed by s_barrier + asm memory
//      fence BEFORE the ds_reads (vmcnt is per-wave; cross-wave landing
//      guarantee requires all-waves-wait -> barrier -> read).
//  Ring: during tile u stage (u+1) quarters A_P0(ph0), B_Q0(ph1),
//  B_Q1(ph2), A_P1(ph3) into buf[(u+1)&1] only. Waits: vmcnt(4) at
//  ph1/ph2 entry + boundary (>=3 phases flight each); last tile
//  vmcnt(2)/vmcnt(0). No lgkmcnt pins (m141). setprio around MFMA.

#define BATCH 64
#define SEQ   196
#define CH    768
#define NHEAD 12
#define HDIM  64
#define TOPK  16
#define HID   3072
#define MROWS 12544
#define MHALF 6272
#define SCALE_F 0.125f  // 64^-0.5
#define NEGBIG -3e38f

typedef __bf16 bf16x8 __attribute__((ext_vector_type(8)));
typedef float  f32x4  __attribute__((ext_vector_type(4)));

__device__ __forceinline__ unsigned short f2b(float f) {
    union { float f; unsigned int i; } c; c.f = f;
    unsigned int u = c.i;
    return (unsigned short)((u + 0x7fffu + ((u >> 16) & 1u)) >> 16); // RNE
}
__device__ __forceinline__ float b2f(unsigned short u) {
    union { unsigned int i; float f; } c; c.i = ((unsigned int)u) << 16; return c.f;
}

// tanh-form GELU, |err vs exact erf-GELU| < 4e-4, ~10 VALU ops.
__device__ __forceinline__ float gelu_f(float v) {
    float u = v * (0.7978845608f + 0.0356774081f * v * v);
    float e = __expf(2.0f * u);
    float th = 1.0f - 2.0f / (e + 1.0f);
    return 0.5f * v * (1.0f + th);
}

// async global->LDS, 16B per lane. LDS base must be wave-uniform; HW adds lane*16.
__device__ __forceinline__ void async16(const unsigned short* g, unsigned short* l) {
    __builtin_amdgcn_global_load_lds(
        (const __attribute__((address_space(1))) unsigned int*)(g),
        (__attribute__((address_space(3))) unsigned int*)(l), 16, 0, 0);
}

// ---------------- all-weights f32 -> bf16, one dispatch ----------------
__global__ __launch_bounds__(256) void f2b4_k(const float* __restrict__ s0, unsigned short* __restrict__ d0, int n0,
                                              const float* __restrict__ s1, unsigned short* __restrict__ d1, int n1,
                                              const float* __restrict__ s2, unsigned short* __restrict__ d2, int n2,
                                              const float* __restrict__ s3, unsigned short* __restrict__ d3, int n3)
{
    int idx = (blockIdx.x * 256 + threadIdx.x) * 4;
    const float* s; unsigned short* d; int n;
    if (idx < n0) { s = s0; d = d0; n = n0; }
    else {
        idx -= n0;
        if (idx < n1) { s = s1; d = d1; n = n1; }
        else {
            idx -= n1;
            if (idx < n2) { s = s2; d = d2; n = n2; }
            else { idx -= n2; s = s3; d = d3; n = n3; }
        }
    }
    if (idx < n) {
        float4 v = *(const float4*)(s + idx);
        ushort4 o;
        o.x = f2b(v.x); o.y = f2b(v.y); o.z = f2b(v.z); o.w = f2b(v.w);
        *(ushort4*)(d + idx) = o;
    }
}

// ---------------- LayerNorm: f32|bf16 in -> bf16 out, one block per row ----------------
template<bool INF32>
__global__ __launch_bounds__(256) void ln_k(const void* __restrict__ xin,
                                            const float* __restrict__ gw,
                                            const float* __restrict__ bw,
                                            unsigned short* __restrict__ out)
{
    const int row = blockIdx.x;
    const int tid = threadIdx.x;
    float v0, v1, v2;
    if constexpr (INF32) {
        const float* xr = (const float*)xin + (size_t)row * CH;
        v0 = xr[tid]; v1 = xr[tid + 256]; v2 = xr[tid + 512];
    } else {
        const unsigned short* xr = (const unsigned short*)xin + (size_t)row * CH;
        v0 = b2f(xr[tid]); v1 = b2f(xr[tid + 256]); v2 = b2f(xr[tid + 512]);
    }
    float s  = v0 + v1 + v2;
    float sq = v0*v0 + v1*v1 + v2*v2;
#pragma unroll
    for (int off = 32; off > 0; off >>= 1) {
        s  += __shfl_down(s, off, 64);
        sq += __shfl_down(sq, off, 64);
    }
    __shared__ __align__(16) float red[8];
    if ((tid & 63) == 0) { red[(tid >> 6) * 2] = s; red[(tid >> 6) * 2 + 1] = sq; }
    __syncthreads();
    s  = red[0] + red[2] + red[4] + red[6];
    sq = red[1] + red[3] + red[5] + red[7];
    float mu  = s * (1.0f / CH);
    float var = sq * (1.0f / CH) - mu * mu;
    float rs  = rsqrtf(var + 1e-5f);
    unsigned short* orow = out + (size_t)row * CH;
    orow[tid]       = f2b((v0 - mu) * rs * gw[tid]       + bw[tid]);
    orow[tid + 256] = f2b((v1 - mu) * rs * gw[tid + 256] + bw[tid + 256]);
    orow[tid + 512] = f2b((v2 - mu) * rs * gw[tid + 512] + bw[tid + 512]);
}

// ---------------- NT GEMM (legacy 2-barrier): C = A @ W^T (+bias)(+gelu)(+resid) ----
// Kept for attn-proj (K=192) and halved fallback paths (M=6272 not /256).
template<int TM, int TN, bool BIAS, int RES, bool GELU, bool OUTF>
__global__ __launch_bounds__(256, 4)
void gemm_bt(const unsigned short* __restrict__ A,
             const unsigned short* __restrict__ Bw,
             const float* __restrict__ bias,
             const void* __restrict__ resid,
             void* __restrict__ Cout,
             int M, int N, int K)
{
    constexpr int WROWS = (TM == 128) ? 2 : 1;
    constexpr int WCOLS = 4 / WROWS;
    constexpr int JF = TN / (16 * WCOLS);           // frag cols per wave
    __shared__ __align__(16) unsigned short As[2][TM * 32];
    __shared__ __align__(16) unsigned short Bs[2][TN * 32];
    const int tid  = threadIdx.x;
    const int w    = tid >> 6;
    const int lane = tid & 63;

    const int gridN = gridDim.x, gridM = gridDim.y;
    const int lid = blockIdx.y * gridN + blockIdx.x;
    const int SG = 8 * gridN;
    const int sg = lid / SG, r = lid % SG;
    const int remM = gridM - sg * 8;
    int mloc, nloc;
    if (remM >= 8) { mloc = sg * 8 + (r & 7); nloc = r >> 3; }
    else           { mloc = sg * 8 + r % remM; nloc = r / remM; }
    const int tileM = mloc * TM;
    const int tileN = nloc * TN;

    const int wm = (w / WCOLS) * 64;                // TM=64 -> 0
    const int wn = (w % WCOLS) * (JF * 16);
    const int q   = lane >> 4;
    const int l16 = lane & 15;
    const int csw = (q ^ (l16 & 3)) * 8;            // swizzled chunk offset for frag reads

    f32x4 acc[4][JF];
#pragma unroll
    for (int i = 0; i < 4; ++i)
#pragma unroll
        for (int j = 0; j < JF; ++j) acc[i][j] = (f32x4){0.f, 0.f, 0.f, 0.f};

    const int r0 = tid >> 2;
    const int g0 = ((tid & 3) ^ (r0 & 3)) * 8;

    const unsigned short* pB[TN / 64];
    const unsigned short* pA[TM / 64];
#pragma unroll
    for (int c = 0; c < TN / 64; ++c) pB[c] = Bw + (size_t)(tileN + r0 + c * 64) * K + g0;
#pragma unroll
    for (int c = 0; c < TM / 64; ++c) pA[c] = A + (size_t)(tileM + r0 + c * 64) * K + g0;

    auto stage = [&](int buf) {
#pragma unroll
        for (int c = 0; c < TN / 64; ++c) {
            async16(pB[c], &Bs[buf][(size_t)(c * 256 + w * 64) * 8]);
            pB[c] += 32;
        }
#pragma unroll
        for (int c = 0; c < TM / 64; ++c) {
            async16(pA[c], &As[buf][(size_t)(c * 256 + w * 64) * 8]);
            pA[c] += 32;
        }
    };

    const int kIters = K >> 5;
    stage(0);
    int cur = 0;
    for (int kt = 0; kt < kIters; ++kt) {
        __syncthreads();
        if (kt + 1 < kIters) stage(cur ^ 1);
        bf16x8 af[4], bfr[JF];
#pragma unroll
        for (int i = 0; i < 4; ++i)
            af[i] = *(const bf16x8*)&As[cur][(wm + i * 16 + l16) * 32 + csw];
#pragma unroll
        for (int j = 0; j < JF; ++j)
            bfr[j] = *(const bf16x8*)&Bs[cur][(wn + j * 16 + l16) * 32 + csw];
#pragma unroll
        for (int i = 0; i < 4; ++i)
#pragma unroll
            for (int j = 0; j < JF; ++j)
                acc[i][j] = __builtin_amdgcn_mfma_f32_16x16x32_bf16(af[i], bfr[j], acc[i][j], 0, 0, 0);
        cur ^= 1;
    }

#pragma unroll
    for (int i = 0; i < 4; ++i) {
#pragma unroll
        for (int r2 = 0; r2 < 4; ++r2) {
            int row = tileM + wm + i * 16 + q * 4 + r2;
#pragma unroll
            for (int j = 0; j < JF; ++j) {
                int col = tileN + wn + j * 16 + l16;
                float v = acc[i][j][r2];
                if (BIAS) v += bias[col];
                if (GELU) v = gelu_f(v);
                if (RES == 1) v += ((const float*)resid)[(size_t)row * N + col];
                if (RES == 2) v += b2f(((const unsigned short*)resid)[(size_t)row * N + col]);
                if (OUTF) ((float*)Cout)[(size_t)row * N + col] = v;
                else      ((unsigned short*)Cout)[(size_t)row * N + col] = f2b(v);
            }
        }
    }
}

// ---------------- 8-phase 256x256 NT GEMM (T3+T4+T5) ----------------
// C[M,N] = A[M,KC] @ W[N,KC]^T (+bias)(+gelu)(+resid). M,N % 256 == 0, KC % 64 == 0.
// 512 threads = 8 waves (2M x 4N); per-wave 128x64 output = acc[8][4] f32x4.
// LDS: 2 dbuf x 256x64 bf16 for A and B = 128 KiB (1 block/CU).
//
// Phase -> data (derived from wave layout wm in {0,128}, wn in {0,64,128,192}):
//   ph0 reads A rows bit6==0 (quarter A_P0) + B rows bit5==0 (B_Q0)
//   ph1 reads B rows bit5==1 (B_Q1)
//   ph2 reads A rows bit6==1 (A_P1)
//   ph3 reads nothing (regs b0 from ph0, af from ph2)
// Stage ring during tile u (all into buf[(u+1)&1], never the current buf):
//   ph0: A_P0(u+1), ph1: B_Q0(u+1), ph2: B_Q1(u+1), ph3: A_P1(u+1).
// Waits (loads; each stage = 2): vmcnt(4)+barrier at ph1 entry (forces
// B_Q1(u)), ph2 entry (forces A_P1(u)), tile boundary (forces A_P0,B_Q0 of
// u+1). Last tile: vmcnt(2)/vmcnt(0) (no newer stages push the queue).
// Each wait is followed by s_barrier + asm memory fence BEFORE the ds_reads
// (vmcnt is per-wave; cross-wave landing needs all-wait -> barrier -> read).
// WAR on stages: all ds_reads of a buffer are register-delivered before that
// tile's ph2 MFMAs (compiler lgkmcnt), >=1 barrier before any overwrite.
template<int KC, bool BIAS, int RES, bool GELU, bool OUTF>
__global__ __launch_bounds__(512, 2)
void gemm8p(const unsigned short* __restrict__ A,
            const unsigned short* __restrict__ Bw,
            const float* __restrict__ bias,
            const void* __restrict__ resid,
            void* __restrict__ Cout,
            int M, int N)
{
    constexpr int T = KC / 64;
    __shared__ __align__(16) unsigned short As[2][256 * 64];
    __shared__ __align__(16) unsigned short Bs[2][256 * 64];
    const int tid  = threadIdx.x;
    const int w    = tid >> 6;
    const int lane = tid & 63;
    const int q    = lane >> 4;
    const int l16  = lane & 15;

    // XCD-locality remap: 8 M-stripes per supergroup; same-stripe blocks share XCD.
    const int gridN = gridDim.x, gridM = gridDim.y;
    const int lid = blockIdx.y * gridN + blockIdx.x;
    const int SG = 8 * gridN;
    const int sg = lid / SG, rr = lid % SG;
    const int remM = gridM - sg * 8;
    int mloc, nloc;
    if (remM >= 8) { mloc = sg * 8 + (rr & 7); nloc = rr >> 3; }
    else           { mloc = sg * 8 + rr % remM; nloc = rr / remM; }
    const int tileM = mloc * 256, tileN = nloc * 256;

    const int wm = (w >> 2) * 128;   // wave row offset (2 rows of waves)
    const int wn = (w & 3) * 64;     // wave col offset (4 cols of waves)

    // staging source (pre-swizzled): per 64-row DMA round, thread t covers
    // row r0 = t>>3, LDS chunk slot t&7 -> global chunk g0 = (t&7)^(r0&7).
    const int r0 = tid >> 3;
    const int g0 = (tid & 7) ^ (r0 & 7);
    const int rB = r0 + (r0 & 32);            // B round rows: {0..31, 64..95}
    const unsigned short* pAsrc = A  + (size_t)(tileM + r0) * KC + g0 * 8;
    const unsigned short* pBsrc = Bw + (size_t)(tileN + rB) * KC + g0 * 8;

    // A quarter j: LDS rows {j*64..j*64+63} u {128+j*64..191+j*64}
    auto stageA = [&](int v, int j) {
        const unsigned short* s = pAsrc + (size_t)(j * 64) * KC + v * 64;
        unsigned short* d = As[v & 1] + j * 4096 + w * 512;
        async16(s, d);
        async16(s + (size_t)128 * KC, d + 8192);
    };
    // B quarter j: LDS rows (bit5==j): {j*32+0..31, j*32+64..95, +128 ...}
    auto stageB = [&](int v, int j) {
        const unsigned short* s = pBsrc + (size_t)(j * 32) * KC + v * 64;
        unsigned short* d = Bs[v & 1] + j * 2048 + (w * 8 + ((w & 4) << 3)) * 64;
        async16(s, d);
        async16(s + (size_t)128 * KC, d + 8192);
    };

    f32x4 acc[8][4];
#pragma unroll
    for (int i = 0; i < 8; ++i)
#pragma unroll
        for (int jn = 0; jn < 4; ++jn) acc[i][jn] = (f32x4){0.f, 0.f, 0.f, 0.f};

    // prologue: tile0 quarters in ring order; A_P0,B_Q0 landed; B_Q1,A_P1 fly.
    stageA(0, 0); stageB(0, 0); stageB(0, 1); stageA(0, 1);
    asm volatile("s_waitcnt vmcnt(4)" ::: "memory");
    __builtin_amdgcn_s_barrier();
    asm volatile("" ::: "memory");

    const int arow = wm + l16;
    const int brow = wn + l16;
    const int xsw  = l16 & 7;

#pragma unroll 2
    for (int u = 0; u < T; ++u) {
        const unsigned short* Ab = As[u & 1];
        const unsigned short* Bb = Bs[u & 1];
        bf16x8 af[4][2], b0[2][2], b1[2][2];

        // ---------- ph0: reads A_P0 + B_Q0 (12); stage A_P0(u+1); MFMA (m0,n0) ----------
#pragma unroll
        for (int m = 0; m < 4; ++m)
#pragma unroll
            for (int kk = 0; kk < 2; ++kk)
                af[m][kk] = *(const bf16x8*)&Ab[(arow + m * 16) * 64 + ((((kk << 2) | q) ^ xsw) << 3)];
#pragma unroll
        for (int n = 0; n < 2; ++n)
#pragma unroll
            for (int kk = 0; kk < 2; ++kk)
                b0[n][kk] = *(const bf16x8*)&Bb[(brow + n * 16) * 64 + ((((kk << 2) | q) ^ xsw) << 3)];
        if (u + 1 < T) stageA(u + 1, 0);
        __builtin_amdgcn_s_setprio(1);
#pragma unroll
        for (int kk = 0; kk < 2; ++kk)
#pragma unroll
            for (int m = 0; m < 4; ++m)
#pragma unroll
                for (int n = 0; n < 2; ++n)
                    acc[m][n] = __builtin_amdgcn_mfma_f32_16x16x32_bf16(af[m][kk], b0[n][kk], acc[m][n], 0, 0, 0);
        __builtin_amdgcn_s_setprio(0);

        // ---------- ph1: wait B_Q1(u); reads b1 (4); stage B_Q0(u+1); MFMA (m0,n1) ----------
        if (u + 1 < T) asm volatile("s_waitcnt vmcnt(4)" ::: "memory");
        else           asm volatile("s_waitcnt vmcnt(2)" ::: "memory");
        __builtin_amdgcn_s_barrier();
        asm volatile("" ::: "memory");
#pragma unroll
        for (int n = 0; n < 2; ++n)
#pragma unroll
            for (int kk = 0; kk < 2; ++kk)
                b1[n][kk] = *(const bf16x8*)&Bb[(brow + 32 + n * 16) * 64 + ((((kk << 2) | q) ^ xsw) << 3)];
        if (u + 1 < T) stageB(u + 1, 0);
        __builtin_amdgcn_s_setprio(1);
#pragma unroll
        for (int kk = 0; kk < 2; ++kk)
#pragma unroll
            for (int m = 0; m < 4; ++m)
#pragma unroll
                for (int n = 0; n < 2; ++n)
                    acc[m][2 + n] = __builtin_amdgcn_mfma_f32_16x16x32_bf16(af[m][kk], b1[n][kk], acc[m][2 + n], 0, 0, 0);
        __builtin_amdgcn_s_setprio(0);

        // ---------- ph2: wait A_P1(u); reads af q1 (8); stage B_Q1(u+1); MFMA (m1,n1) ----------
        if (u + 1 < T) asm volatile("s_waitcnt vmcnt(4)" ::: "memory");
        else           asm volatile("s_waitcnt vmcnt(0)" ::: "memory");
        __builtin_amdgcn_s_barrier();
        asm volatile("" ::: "memory");
#pragma unroll
        for (int m = 0; m < 4; ++m)
#pragma unroll
            for (int kk = 0; kk < 2; ++kk)
                af[m][kk] = *(const bf16x8*)&Ab[(arow + 64 + m * 16) * 64 + ((((kk << 2) | q) ^ xsw) << 3)];
        if (u + 1 < T) stageB(u + 1, 1);
        __builtin_amdgcn_s_setprio(1);
#pragma unroll
        for (int kk = 0; kk < 2; ++kk)
#pragma unroll
            for (int m = 0; m < 4; ++m)
#pragma unroll
                for (int n = 0; n < 2; ++n)
                    acc[4 + m][2 + n] = __builtin_amdgcn_mfma_f32_16x16x32_bf16(af[m][kk], b1[n][kk], acc[4 + m][2 + n], 0, 0, 0);
        __builtin_amdgcn_s_setprio(0);

        // ---------- ph3: stage A_P1(u+1); boundary wait; MFMA (m1,n0) ----------
        if (u + 1 < T) {
            stageA(u + 1, 1);
            asm volatile("s_waitcnt vmcnt(4)" ::: "memory");  // A_P0,B_Q0 of u+1 landed
            __builtin_amdgcn_s_barrier();
            asm volatile("" ::: "memory");
        }
        __builtin_amdgcn_s_setprio(1);
#pragma unroll
        for (int kk = 0; kk < 2; ++kk)
#pragma unroll
            for (int m = 0; m < 4; ++m)
#pragma unroll
                for (int n = 0; n < 2; ++n)
                    acc[4 + m][n] = __builtin_amdgcn_mfma_f32_16x16x32_bf16(af[m][kk], b0[n][kk], acc[4 + m][n], 0, 0, 0);
        __builtin_amdgcn_s_setprio(0);
    }

    // ---------------- epilogue ----------------
#pragma unroll
    for (int mh = 0; mh < 2; ++mh)
#pragma unroll
        for (int m = 0; m < 4; ++m)
#pragma unroll
            for (int r2 = 0; r2 < 4; ++r2) {
                const int row = tileM + wm + mh * 64 + m * 16 + q * 4 + r2;
#pragma unroll
                for (int nh = 0; nh < 2; ++nh)
#pragma unroll
                    for (int n = 0; n < 2; ++n) {
                        const int col = tileN + wn + nh * 32 + n * 16 + l16;
                        float v = acc[mh * 4 + m][nh * 2 + n][r2];
                        if (BIAS) v += bias[col];
                        if (GELU) v = gelu_f(v);
                        if (RES == 1) v += ((const float*)resid)[(size_t)row * N + col];
                        if (RES == 2) v += b2f(((const unsigned short*)resid)[(size_t)row * N + col]);
                        if (OUTF) ((float*)Cout)[(size_t)row * N + col] = v;
                        else      ((unsigned short*)Cout)[(size_t)row * N + col] = f2b(v);
                    }
            }
    (void)M;
}

// ---------------- Attention: MFMA scores + in-register top-16 + softmax ----------------
__global__ __launch_bounds__(256) void attn_topk(const unsigned short* __restrict__ qk,
                                                 unsigned short* __restrict__ aout)
{
    const int bh = blockIdx.x;
    const int b = bh / NHEAD, h = bh % NHEAD;
    __shared__ __align__(16) unsigned short Qs[208 * 64];
    __shared__ __align__(16) unsigned short Ks[208 * 64];
    const int tid = threadIdx.x;

    for (int i = tid; i < 208 * 8; i += 256) {
        int row = i >> 3, c = i & 7;
        uint4 vq = make_uint4(0, 0, 0, 0), vk = vq;
        if (row < SEQ) {
            const uint4* gp = (const uint4*)(qk + ((size_t)(b * SEQ + row) * 1536 + h * 64));
            vq = gp[c];        // q half
            vk = gp[c + 96];   // k half: +768 shorts = +96 uint4
        }
        int slot = c ^ (row & 7);
        *(uint4*)&Qs[row * 64 + slot * 8] = vq;
        *(uint4*)&Ks[row * 64 + slot * 8] = vk;
    }
    __syncthreads();

    const int w = tid >> 6, lane = tid & 63;
    const int q = lane >> 4, l16 = lane & 15;

    for (int tn = w; tn < 13; tn += 4) {
        const int nrow = tn * 16 + l16;
        const int nsw = nrow & 7;
        bf16x8 bq0 = *(const bf16x8*)&Qs[nrow * 64 + ((0 * 4 + q) ^ nsw) * 8];
        bf16x8 bq1 = *(const bf16x8*)&Qs[nrow * 64 + ((1 * 4 + q) ^ nsw) * 8];

        float t[TOPK];
#pragma unroll
        for (int j = 0; j < TOPK; ++j) t[j] = NEGBIG;

        for (int tm = 0; tm < 12; ++tm) {
            const int mrow = tm * 16 + l16;
            const int msw = mrow & 7;
            bf16x8 ak0 = *(const bf16x8*)&Ks[mrow * 64 + ((0 * 4 + q) ^ msw) * 8];
            bf16x8 ak1 = *(const bf16x8*)&Ks[mrow * 64 + ((1 * 4 + q) ^ msw) * 8];
            f32x4 acc = (f32x4){0.f, 0.f, 0.f, 0.f};
            acc = __builtin_amdgcn_mfma_f32_16x16x32_bf16(ak0, bq0, acc, 0, 0, 0);
            acc = __builtin_amdgcn_mfma_f32_16x16x32_bf16(ak1, bq1, acc, 0, 0, 0);
#pragma unroll
            for (int r = 0; r < 4; ++r) {
                float v = acc[r];
#pragma unroll
                for (int j = 0; j < TOPK; ++j) {
                    float mx = fmaxf(t[j], v);
                    v = fminf(t[j], v);
                    t[j] = mx;
                }
            }
        }
        {   // m-tile 12: m = 192 + q*4 + r valid only for q==0
            const int mrow = 12 * 16 + l16;
            const int msw = mrow & 7;
            bf16x8 ak0 = *(const bf16x8*)&Ks[mrow * 64 + ((0 * 4 + q) ^ msw) * 8];
            bf16x8 ak1 = *(const bf16x8*)&Ks[mrow * 64 + ((1 * 4 + q) ^ msw) * 8];
            f32x4 acc = (f32x4){0.f, 0.f, 0.f, 0.f};
            acc = __builtin_amdgcn_mfma_f32_16x16x32_bf16(ak0, bq0, acc, 0, 0, 0);
            acc = __builtin_amdgcn_mfma_f32_16x16x32_bf16(ak1, bq1, acc, 0, 0, 0);
#pragma unroll
            for (int r = 0; r < 4; ++r) {
                float v = (q == 0) ? acc[r] : NEGBIG;
#pragma unroll
                for (int j = 0; j < TOPK; ++j) {
                    float mx = fmaxf(t[j], v);
                    v = fminf(t[j], v);
                    t[j] = mx;
                }
            }
        }

#pragma unroll
        for (int stage = 0; stage < 2; ++stage) {
            const int xm = 16 << stage;
            float bl[TOPK], c[TOPK];
#pragma unroll
            for (int j = 0; j < TOPK; ++j) bl[j] = __shfl_xor(t[j], xm, 64);
#pragma unroll
            for (int j = 0; j < TOPK; ++j) c[j] = fmaxf(t[j], bl[TOPK - 1 - j]);
#pragma unroll
            for (int s = 8; s >= 1; s >>= 1) {
#pragma unroll
                for (int i = 0; i < TOPK; ++i) {
                    if ((i & s) == 0) {
                        float mx = fmaxf(c[i], c[i + s]);
                        c[i + s] = fminf(c[i], c[i + s]);
                        c[i] = mx;
                    }
                }
            }
#pragma unroll
            for (int j = 0; j < TOPK; ++j) t[j] = c[j];
        }

        if (q == 0 && nrow < SEQ) {
            float e[TOPK], sum = 0.f;
#pragma unroll
            for (int j = 0; j < TOPK; ++j) { e[j] = __expf((t[j] - t[0]) * SCALE_F); sum += e[j]; }
            float inv = 1.0f / sum;
            unsigned int pk[8];
#pragma unroll
            for (int jj = 0; jj < 8; ++jj)
                pk[jj] = (unsigned int)f2b(e[2 * jj] * inv) |
                         ((unsigned int)f2b(e[2 * jj + 1] * inv) << 16);
            unsigned short* dst = aout + ((size_t)(b * SEQ + nrow)) * (NHEAD * TOPK) + h * TOPK;
            ((uint4*)dst)[0] = make_uint4(pk[0], pk[1], pk[2], pk[3]);
            ((uint4*)dst)[1] = make_uint4(pk[4], pk[5], pk[6], pk[7]);
        }
    }
}

// ---------------- Launch ----------------
extern "C" void kernel_launch(void* const* d_in, const int* in_sizes, int n_in,
                              void* d_out, int out_size, void* d_ws, size_t ws_size,
                              hipStream_t stream)
{
    const float* x    = (const float*)d_in[0];
    const float* g1   = (const float*)d_in[1];
    const float* bb1  = (const float*)d_in[2];
    const float* qkw  = (const float*)d_in[3];
    const float* pw   = (const float*)d_in[4];
    const float* pb   = (const float*)d_in[5];
    const float* g2   = (const float*)d_in[6];
    const float* bb2  = (const float*)d_in[7];
    const float* f1w  = (const float*)d_in[8];
    const float* f1b  = (const float*)d_in[9];
    const float* f2w  = (const float*)d_in[10];
    const float* f2bp = (const float*)d_in[11];
    float* out = (float*)d_out;

    // layout: hbuf | weights(wqk,wp,wf1,wf2) | av | qk/gg | x1b
    char* ws = (char*)d_ws;
    const size_t SZ_H   = (size_t)MROWS * CH * 2;              // 19,267,584
    const size_t N_WQK  = (size_t)2 * CH * CH;
    const size_t N_WP   = (size_t)CH * (NHEAD * TOPK);
    const size_t N_WF   = (size_t)HID * CH;
    const size_t SZ_W   = (N_WQK + N_WP + 2 * N_WF) * 2;       // 12,091,392
    const size_t SZ_A   = (size_t)MROWS * (NHEAD * TOPK) * 2;  //  4,816,896
    const size_t SZ_QK  = (size_t)MROWS * 2 * CH * 2;          // 38,535,168
    const size_t SZ_GGF = (size_t)MROWS * HID * 2;             // 77,070,336

    unsigned short* hbuf = (unsigned short*)(ws);
    unsigned short* wqk  = (unsigned short*)(ws + SZ_H);
    unsigned short* wp   = wqk + N_WQK;
    unsigned short* wf1  = wp  + N_WP;
    unsigned short* wf2  = wf1 + N_WF;
    unsigned short* av   = (unsigned short*)(ws + SZ_H + SZ_W);
    unsigned short* qk   = (unsigned short*)(ws + SZ_H + SZ_W + SZ_A);
    unsigned short* gg   = qk;   // overlays qk (dead by MLP time)

    const size_t base = SZ_H + SZ_W + SZ_A;
    const bool fullMLP = ws_size >= base + SZ_GGF + SZ_H;      // 132.5 MB: full-M + bf16 x1
    const bool bx1     = fullMLP || ws_size >= base + SZ_QK + SZ_H;  // 94 MB: halves + bf16 x1
    unsigned short* x1b = (unsigned short*)(ws + base + (fullMLP ? SZ_GGF : SZ_QK));
    float* x1 = out;   // f32 fallback residual lives in d_out

    // 0) all weights f32 -> bf16, one dispatch
    {
        int total4 = (int)((N_WQK + N_WP + 2 * N_WF) / 4);
        f2b4_k<<<(total4 + 255) / 256, 256, 0, stream>>>(
            qkw, wqk, (int)N_WQK, pw, wp, (int)N_WP,
            f1w, wf1, (int)N_WF, f2w, wf2, (int)N_WF);
    }

    // 1) LN1: x(f32) -> h (bf16)
    ln_k<true><<<MROWS, 256, 0, stream>>>(x, g1, bb1, hbuf);
    // 2) qk = h @ qk_w^T   [12544 x 1536], K=768   (8-phase 256^2: grid 6x49)
    gemm8p<CH, false, 0, false, false><<<dim3(2 * CH / 256, MROWS / 256), 512, 0, stream>>>(
        hbuf, wqk, nullptr, nullptr, qk, MROWS, 2 * CH);
    // 3) attention -> top16 softmax weights [12544 x 192] bf16
    attn_topk<<<BATCH * NHEAD, 256, 0, stream>>>(qk, av);

    if (bx1) {
        // 4) x1b = bf16(x + a @ attn_proj_w^T + b)   (64x128: grid 6x196)
        gemm_bt<64, 128, true, 1, false, false><<<dim3(6, 196), 256, 0, stream>>>(
            av, wp, pb, x, x1b, MROWS, CH, NHEAD * TOPK);
        // 5) LN2: x1b (bf16) -> h2
        ln_k<false><<<MROWS, 256, 0, stream>>>(x1b, g2, bb2, hbuf);
        if (fullMLP) {
            // fc1: [12544 x 3072], K=768  (8-phase 256^2: grid 12x49)
            gemm8p<CH, true, 0, true, false><<<dim3(HID / 256, MROWS / 256), 512, 0, stream>>>(
                hbuf, wf1, f1b, nullptr, gg, MROWS, HID);
            // fc2: [12544 x 768], K=3072 (8-phase 256^2: grid 3x49)
            gemm8p<HID, true, 2, false, true><<<dim3(CH / 256, MROWS / 256), 512, 0, stream>>>(
                gg, wf2, f2bp, x1b, out, MROWS, CH);
        } else {
            for (int half = 0; half < 2; ++half) {
                const size_t ro = (size_t)half * MHALF;
                gemm_bt<128, 128, true, 0, true, false><<<dim3(24, 49), 256, 0, stream>>>(
                    hbuf + ro * CH, wf1, f1b, nullptr, gg, MHALF, HID, CH);
                gemm_bt<64, 256, true, 2, false, true><<<dim3(3, 98), 256, 0, stream>>>(
                    gg, wf2, f2bp, x1b + ro * CH, out + ro * CH, MHALF, CH, HID);
            }
        }
    } else {
        // conservative fallback: f32 x1 in d_out, halved MLP (74.7 MB ws)
        gemm_bt<64, 128, true, 1, false, true><<<dim3(6, 196), 256, 0, stream>>>(
            av, wp, pb, x, x1, MROWS, CH, NHEAD * TOPK);
        ln_k<true><<<MROWS, 256, 0, stream>>>(x1, g2, bb2, hbuf);
        for (int half = 0; half < 2; ++half) {
            const size_t ro = (size_t)half * MHALF;
            gemm_bt<128, 128, true, 0, true, false><<<dim3(24, 49), 256, 0, stream>>>(
                hbuf + ro * CH, wf1, f1b, nullptr, gg, MHALF, HID, CH);
            gemm_bt<64, 256, true, 1, false, true><<<dim3(3, 98), 256, 0, stream>>>(
                gg, wf2, f2bp, x1 + ro * CH, out + ro * CH, MHALF, CH, HID);
        }
    }
}

// Round 4
// 416.503 us; speedup vs baseline: 1.0771x; 1.0487x over previous
//
#include <hip/hip_runtime.h>

// Block_58394375356873: HomoAttention transformer block, MI355X gfx950.
// I/O dtype: float32 (per reference). Internal GEMM compute: bf16 MFMA.
// M = B*N = 64*196 = 12544.
//
// R4: gemm8p made persistent + coalesced epilogue.
//  - Persistent: <=256 blocks loop over tiles; at u=T-1 the stage ring
//    redirects to the next tile's K-tile 0 (T even -> buffer parity aligns),
//    so the steady vmcnt(4) pattern continues across tile boundaries.
//    Prologue fill paid once per block; next tile's DMA overlaps epilogue.
//    Epilogue ends with vmcnt(4) (drain its stores, keep 4 staged loads in
//    flight) so the K-loop's counted waits stay exact.
//  - Epilogue: acc -> per-wave LDS slab (in buf1; DMA targets buf0) ->
//    coalesced 16B/lane global_store_dwordx4 (16 stores/thread vs 128
//    scalar 2B). Resid/bias applied in the coalesced pass.

#define BATCH 64
#define SEQ   196
#define CH    768
#define NHEAD 12
#define HDIM  64
#define TOPK  16
#define HID   3072
#define MROWS 12544
#define MHALF 6272
#define SCALE_F 0.125f  // 64^-0.5
#define NEGBIG -3e38f

typedef __bf16 bf16x8 __attribute__((ext_vector_type(8)));
typedef float  f32x4  __attribute__((ext_vector_type(4)));

__device__ __forceinline__ unsigned short f2b(float f) {
    union { float f; unsigned int i; } c; c.f = f;
    unsigned int u = c.i;
    return (unsigned short)((u + 0x7fffu + ((u >> 16) & 1u)) >> 16); // RNE
}
__device__ __forceinline__ float b2f(unsigned short u) {
    union { unsigned int i; float f; } c; c.i = ((unsigned int)u) << 16; return c.f;
}

// tanh-form GELU, |err vs exact erf-GELU| < 4e-4, ~10 VALU ops.
__device__ __forceinline__ float gelu_f(float v) {
    float u = v * (0.7978845608f + 0.0356774081f * v * v);
    float e = __expf(2.0f * u);
    float th = 1.0f - 2.0f / (e + 1.0f);
    return 0.5f * v * (1.0f + th);
}

// async global->LDS, 16B per lane. LDS base must be wave-uniform; HW adds lane*16.
__device__ __forceinline__ void async16(const unsigned short* g, unsigned short* l) {
    __builtin_amdgcn_global_load_lds(
        (const __attribute__((address_space(1))) unsigned int*)(g),
        (__attribute__((address_space(3))) unsigned int*)(l), 16, 0, 0);
}

// ---------------- all-weights f32 -> bf16, one dispatch ----------------
__global__ __launch_bounds__(256) void f2b4_k(const float* __restrict__ s0, unsigned short* __restrict__ d0, int n0,
                                              const float* __restrict__ s1, unsigned short* __restrict__ d1, int n1,
                                              const float* __restrict__ s2, unsigned short* __restrict__ d2, int n2,
                                              const float* __restrict__ s3, unsigned short* __restrict__ d3, int n3)
{
    int idx = (blockIdx.x * 256 + threadIdx.x) * 4;
    const float* s; unsigned short* d; int n;
    if (idx < n0) { s = s0; d = d0; n = n0; }
    else {
        idx -= n0;
        if (idx < n1) { s = s1; d = d1; n = n1; }
        else {
            idx -= n1;
            if (idx < n2) { s = s2; d = d2; n = n2; }
            else { idx -= n2; s = s3; d = d3; n = n3; }
        }
    }
    if (idx < n) {
        float4 v = *(const float4*)(s + idx);
        ushort4 o;
        o.x = f2b(v.x); o.y = f2b(v.y); o.z = f2b(v.z); o.w = f2b(v.w);
        *(ushort4*)(d + idx) = o;
    }
}

// ---------------- LayerNorm: f32|bf16 in -> bf16 out, one block per row ----------------
template<bool INF32>
__global__ __launch_bounds__(256) void ln_k(const void* __restrict__ xin,
                                            const float* __restrict__ gw,
                                            const float* __restrict__ bw,
                                            unsigned short* __restrict__ out)
{
    const int row = blockIdx.x;
    const int tid = threadIdx.x;
    float v0, v1, v2;
    if constexpr (INF32) {
        const float* xr = (const float*)xin + (size_t)row * CH;
        v0 = xr[tid]; v1 = xr[tid + 256]; v2 = xr[tid + 512];
    } else {
        const unsigned short* xr = (const unsigned short*)xin + (size_t)row * CH;
        v0 = b2f(xr[tid]); v1 = b2f(xr[tid + 256]); v2 = b2f(xr[tid + 512]);
    }
    float s  = v0 + v1 + v2;
    float sq = v0*v0 + v1*v1 + v2*v2;
#pragma unroll
    for (int off = 32; off > 0; off >>= 1) {
        s  += __shfl_down(s, off, 64);
        sq += __shfl_down(sq, off, 64);
    }
    __shared__ __align__(16) float red[8];
    if ((tid & 63) == 0) { red[(tid >> 6) * 2] = s; red[(tid >> 6) * 2 + 1] = sq; }
    __syncthreads();
    s  = red[0] + red[2] + red[4] + red[6];
    sq = red[1] + red[3] + red[5] + red[7];
    float mu  = s * (1.0f / CH);
    float var = sq * (1.0f / CH) - mu * mu;
    float rs  = rsqrtf(var + 1e-5f);
    unsigned short* orow = out + (size_t)row * CH;
    orow[tid]       = f2b((v0 - mu) * rs * gw[tid]       + bw[tid]);
    orow[tid + 256] = f2b((v1 - mu) * rs * gw[tid + 256] + bw[tid + 256]);
    orow[tid + 512] = f2b((v2 - mu) * rs * gw[tid + 512] + bw[tid + 512]);
}

// ---------------- NT GEMM (legacy 2-barrier): C = A @ W^T (+bias)(+gelu)(+resid) ----
// Kept for attn-proj (K=192) and halved fallback paths (M=6272 not /256).
template<int TM, int TN, bool BIAS, int RES, bool GELU, bool OUTF>
__global__ __launch_bounds__(256, 4)
void gemm_bt(const unsigned short* __restrict__ A,
             const unsigned short* __restrict__ Bw,
             const float* __restrict__ bias,
             const void* __restrict__ resid,
             void* __restrict__ Cout,
             int M, int N, int K)
{
    constexpr int WROWS = (TM == 128) ? 2 : 1;
    constexpr int WCOLS = 4 / WROWS;
    constexpr int JF = TN / (16 * WCOLS);           // frag cols per wave
    __shared__ __align__(16) unsigned short As[2][TM * 32];
    __shared__ __align__(16) unsigned short Bs[2][TN * 32];
    const int tid  = threadIdx.x;
    const int w    = tid >> 6;
    const int lane = tid & 63;

    const int gridN = gridDim.x, gridM = gridDim.y;
    const int lid = blockIdx.y * gridN + blockIdx.x;
    const int SG = 8 * gridN;
    const int sg = lid / SG, r = lid % SG;
    const int remM = gridM - sg * 8;
    int mloc, nloc;
    if (remM >= 8) { mloc = sg * 8 + (r & 7); nloc = r >> 3; }
    else           { mloc = sg * 8 + r % remM; nloc = r / remM; }
    const int tileM = mloc * TM;
    const int tileN = nloc * TN;

    const int wm = (w / WCOLS) * 64;                // TM=64 -> 0
    const int wn = (w % WCOLS) * (JF * 16);
    const int q   = lane >> 4;
    const int l16 = lane & 15;
    const int csw = (q ^ (l16 & 3)) * 8;            // swizzled chunk offset for frag reads

    f32x4 acc[4][JF];
#pragma unroll
    for (int i = 0; i < 4; ++i)
#pragma unroll
        for (int j = 0; j < JF; ++j) acc[i][j] = (f32x4){0.f, 0.f, 0.f, 0.f};

    const int r0 = tid >> 2;
    const int g0 = ((tid & 3) ^ (r0 & 3)) * 8;

    const unsigned short* pB[TN / 64];
    const unsigned short* pA[TM / 64];
#pragma unroll
    for (int c = 0; c < TN / 64; ++c) pB[c] = Bw + (size_t)(tileN + r0 + c * 64) * K + g0;
#pragma unroll
    for (int c = 0; c < TM / 64; ++c) pA[c] = A + (size_t)(tileM + r0 + c * 64) * K + g0;

    auto stage = [&](int buf) {
#pragma unroll
        for (int c = 0; c < TN / 64; ++c) {
            async16(pB[c], &Bs[buf][(size_t)(c * 256 + w * 64) * 8]);
            pB[c] += 32;
        }
#pragma unroll
        for (int c = 0; c < TM / 64; ++c) {
            async16(pA[c], &As[buf][(size_t)(c * 256 + w * 64) * 8]);
            pA[c] += 32;
        }
    };

    const int kIters = K >> 5;
    stage(0);
    int cur = 0;
    for (int kt = 0; kt < kIters; ++kt) {
        __syncthreads();
        if (kt + 1 < kIters) stage(cur ^ 1);
        bf16x8 af[4], bfr[JF];
#pragma unroll
        for (int i = 0; i < 4; ++i)
            af[i] = *(const bf16x8*)&As[cur][(wm + i * 16 + l16) * 32 + csw];
#pragma unroll
        for (int j = 0; j < JF; ++j)
            bfr[j] = *(const bf16x8*)&Bs[cur][(wn + j * 16 + l16) * 32 + csw];
#pragma unroll
        for (int i = 0; i < 4; ++i)
#pragma unroll
            for (int j = 0; j < JF; ++j)
                acc[i][j] = __builtin_amdgcn_mfma_f32_16x16x32_bf16(af[i], bfr[j], acc[i][j], 0, 0, 0);
        cur ^= 1;
    }

#pragma unroll
    for (int i = 0; i < 4; ++i) {
#pragma unroll
        for (int r2 = 0; r2 < 4; ++r2) {
            int row = tileM + wm + i * 16 + q * 4 + r2;
#pragma unroll
            for (int j = 0; j < JF; ++j) {
                int col = tileN + wn + j * 16 + l16;
                float v = acc[i][j][r2];
                if (BIAS) v += bias[col];
                if (GELU) v = gelu_f(v);
                if (RES == 1) v += ((const float*)resid)[(size_t)row * N + col];
                if (RES == 2) v += b2f(((const unsigned short*)resid)[(size_t)row * N + col]);
                if (OUTF) ((float*)Cout)[(size_t)row * N + col] = v;
                else      ((unsigned short*)Cout)[(size_t)row * N + col] = f2b(v);
            }
        }
    }
}

// ---------------- Persistent 4-phase 256x256 NT GEMM (T3+T4+T5) ----------------
// C[M,N] = A[M,KC] @ W[N,KC]^T (+bias)(+gelu)(+resid). M,N % 256 == 0,
// KC % 128 == 0 (T even). 512 threads = 8 waves (2M x 4N).
// Grid: 1D, P <= 256 persistent blocks; block b does tiles b, b+P, ...
// K-loop skeleton identical to the verified R3 schedule; at u=T-1 the stage
// ring targets the NEXT tile's K-tile 0 (parity aligns since T even).
template<int KC, bool BIAS, int RES, bool GELU, bool OUTF>
__global__ __launch_bounds__(512, 2)
void gemm8p(const unsigned short* __restrict__ A,
            const unsigned short* __restrict__ Bw,
            const float* __restrict__ bias,
            const void* __restrict__ resid,
            void* __restrict__ Cout,
            int M, int N)
{
    constexpr int T = KC / 64;
    static_assert((T & 1) == 0, "T must be even for persistent parity");
    __shared__ __align__(16) unsigned short As[2][256 * 64];
    __shared__ __align__(16) unsigned short Bs[2][256 * 64];
    const int tid  = threadIdx.x;
    const int w    = tid >> 6;
    const int lane = tid & 63;
    const int q    = lane >> 4;
    const int l16  = lane & 15;

    const int gridN = N >> 8, gridM = M >> 8;
    const int nt = gridN * gridM;
    const int P = gridDim.x;

    // XCD-locality remap (t%8 class preserved across a block's tiles).
    auto tileOf = [&](int lid2, int& tm, int& tn) {
        const int SG = 8 * gridN;
        const int sg = lid2 / SG, rr2 = lid2 % SG;
        const int remM = gridM - sg * 8;
        int mloc, nloc;
        if (remM >= 8) { mloc = sg * 8 + (rr2 & 7); nloc = rr2 >> 3; }
        else           { mloc = sg * 8 + rr2 % remM; nloc = rr2 / remM; }
        tm = mloc * 256; tn = nloc * 256;
    };

    const int wm = (w >> 2) * 128;   // wave row offset (2 rows of waves)
    const int wn = (w & 3) * 64;     // wave col offset (4 cols of waves)

    // staging constants (pre-swizzled source): per 64-row DMA round, thread t
    // covers row r0 = t>>3, LDS chunk slot t&7 -> global chunk g0 = (t&7)^(r0&7).
    const int r0 = tid >> 3;
    const int g0 = (tid & 7) ^ (r0 & 7);
    const int rB = r0 + (r0 & 32);            // B round rows: {0..31, 64..95}

    const int arow = wm + l16;
    const int brow = wn + l16;
    const int xsw  = l16 & 7;

    for (int t = (int)blockIdx.x; t < nt; t += P) {
        int tileM, tileN;
        tileOf(t, tileM, tileN);
        const bool hasNext = (t + P) < nt;
        int tileM2 = tileM, tileN2 = tileN;
        if (hasNext) tileOf(t + P, tileM2, tileN2);

        const unsigned short* pA0  = A  + (size_t)(tileM  + r0) * KC + g0 * 8;
        const unsigned short* pB0  = Bw + (size_t)(tileN  + rB) * KC + g0 * 8;
        const unsigned short* pA0n = A  + (size_t)(tileM2 + r0) * KC + g0 * 8;
        const unsigned short* pB0n = Bw + (size_t)(tileN2 + rB) * KC + g0 * 8;

        // A quarter j: LDS rows {j*64..+63} u {128+j*64..+63}; v may be T (=next tile k0)
        auto stageA = [&](int v, int j) {
            const unsigned short* base = (v == T) ? pA0n : pA0;
            const int vv = (v == T) ? 0 : v;
            const unsigned short* s = base + (size_t)(j * 64) * KC + vv * 64;
            unsigned short* d = As[vv & 1] + j * 4096 + w * 512;
            async16(s, d);
            async16(s + (size_t)128 * KC, d + 8192);
        };
        // B quarter j: LDS rows (bit5==j)
        auto stageB = [&](int v, int j) {
            const unsigned short* base = (v == T) ? pB0n : pB0;
            const int vv = (v == T) ? 0 : v;
            const unsigned short* s = base + (size_t)(j * 32) * KC + vv * 64;
            unsigned short* d = Bs[vv & 1] + j * 2048 + (w * 8 + ((w & 4) << 3)) * 64;
            async16(s, d);
            async16(s + (size_t)128 * KC, d + 8192);
        };

        f32x4 acc[8][4];
#pragma unroll
        for (int i = 0; i < 8; ++i)
#pragma unroll
            for (int jn = 0; jn < 4; ++jn) acc[i][jn] = (f32x4){0.f, 0.f, 0.f, 0.f};

        if (t == (int)blockIdx.x) {
            // prologue (first tile only): A_P0,B_Q0 landed; B_Q1,A_P1 fly.
            stageA(0, 0); stageB(0, 0); stageB(0, 1); stageA(0, 1);
            asm volatile("s_waitcnt vmcnt(4)" ::: "memory");
            __builtin_amdgcn_s_barrier();
            asm volatile("" ::: "memory");
        }

#pragma unroll 2
        for (int u = 0; u < T; ++u) {
            const unsigned short* Ab = As[u & 1];
            const unsigned short* Bb = Bs[u & 1];
            const bool more = (u + 1 < T) || hasNext;
            bf16x8 af[4][2], b0[2][2], b1[2][2];

            // ---------- ph0: reads A_P0 + B_Q0; stage A_P0(u+1); MFMA (m0,n0) ----------
#pragma unroll
            for (int m = 0; m < 4; ++m)
#pragma unroll
                for (int kk = 0; kk < 2; ++kk)
                    af[m][kk] = *(const bf16x8*)&Ab[(arow + m * 16) * 64 + ((((kk << 2) | q) ^ xsw) << 3)];
#pragma unroll
            for (int n = 0; n < 2; ++n)
#pragma unroll
                for (int kk = 0; kk < 2; ++kk)
                    b0[n][kk] = *(const bf16x8*)&Bb[(brow + n * 16) * 64 + ((((kk << 2) | q) ^ xsw) << 3)];
            if (more) stageA(u + 1, 0);
            __builtin_amdgcn_s_setprio(1);
#pragma unroll
            for (int kk = 0; kk < 2; ++kk)
#pragma unroll
                for (int m = 0; m < 4; ++m)
#pragma unroll
                    for (int n = 0; n < 2; ++n)
                        acc[m][n] = __builtin_amdgcn_mfma_f32_16x16x32_bf16(af[m][kk], b0[n][kk], acc[m][n], 0, 0, 0);
            __builtin_amdgcn_s_setprio(0);

            // ---------- ph1: wait B_Q1(u); reads b1; stage B_Q0(u+1); MFMA (m0,n1) ----------
            if (more) asm volatile("s_waitcnt vmcnt(4)" ::: "memory");
            else      asm volatile("s_waitcnt vmcnt(2)" ::: "memory");
            __builtin_amdgcn_s_barrier();
            asm volatile("" ::: "memory");
#pragma unroll
            for (int n = 0; n < 2; ++n)
#pragma unroll
                for (int kk = 0; kk < 2; ++kk)
                    b1[n][kk] = *(const bf16x8*)&Bb[(brow + 32 + n * 16) * 64 + ((((kk << 2) | q) ^ xsw) << 3)];
            if (more) stageB(u + 1, 0);
            __builtin_amdgcn_s_setprio(1);
#pragma unroll
            for (int kk = 0; kk < 2; ++kk)
#pragma unroll
                for (int m = 0; m < 4; ++m)
#pragma unroll
                    for (int n = 0; n < 2; ++n)
                        acc[m][2 + n] = __builtin_amdgcn_mfma_f32_16x16x32_bf16(af[m][kk], b1[n][kk], acc[m][2 + n], 0, 0, 0);
            __builtin_amdgcn_s_setprio(0);

            // ---------- ph2: wait A_P1(u); reads af (upper); stage B_Q1(u+1); MFMA (m1,n1) ----------
            if (more) asm volatile("s_waitcnt vmcnt(4)" ::: "memory");
            else      asm volatile("s_waitcnt vmcnt(0)" ::: "memory");
            __builtin_amdgcn_s_barrier();
            asm volatile("" ::: "memory");
#pragma unroll
            for (int m = 0; m < 4; ++m)
#pragma unroll
                for (int kk = 0; kk < 2; ++kk)
                    af[m][kk] = *(const bf16x8*)&Ab[(arow + 64 + m * 16) * 64 + ((((kk << 2) | q) ^ xsw) << 3)];
            if (more) stageB(u + 1, 1);
            __builtin_amdgcn_s_setprio(1);
#pragma unroll
            for (int kk = 0; kk < 2; ++kk)
#pragma unroll
                for (int m = 0; m < 4; ++m)
#pragma unroll
                    for (int n = 0; n < 2; ++n)
                        acc[4 + m][2 + n] = __builtin_amdgcn_mfma_f32_16x16x32_bf16(af[m][kk], b1[n][kk], acc[4 + m][2 + n], 0, 0, 0);
            __builtin_amdgcn_s_setprio(0);

            // ---------- ph3: stage A_P1(u+1); boundary wait; MFMA (m1,n0) ----------
            if (more) {
                stageA(u + 1, 1);
                asm volatile("s_waitcnt vmcnt(4)" ::: "memory");  // A_P0,B_Q0 of u+1 landed
                __builtin_amdgcn_s_barrier();
                asm volatile("" ::: "memory");
            }
            __builtin_amdgcn_s_setprio(1);
#pragma unroll
            for (int kk = 0; kk < 2; ++kk)
#pragma unroll
                for (int m = 0; m < 4; ++m)
#pragma unroll
                    for (int n = 0; n < 2; ++n)
                        acc[4 + m][n] = __builtin_amdgcn_mfma_f32_16x16x32_bf16(af[m][kk], b0[n][kk], acc[4 + m][n], 0, 0, 0);
            __builtin_amdgcn_s_setprio(0);
        }

        // ---------------- coalesced epilogue (slab in buf1; DMA targets buf0) ------
        __syncthreads();   // all waves done with buf1 ds_reads; buf1 -> scratch

        float bshift[2][2];
        if (BIAS) {
#pragma unroll
            for (int nh = 0; nh < 2; ++nh)
#pragma unroll
                for (int n = 0; n < 2; ++n)
                    bshift[nh][n] = bias[tileN + wn + nh * 32 + n * 16 + l16];
        }

        if constexpr (!OUTF) {
            unsigned short* slab = &As[1][0] + (size_t)w * 1152;   // 16 x 72 bf16
            unsigned short* co = (unsigned short*)Cout;
#pragma unroll
            for (int mh = 0; mh < 2; ++mh)
#pragma unroll
                for (int m = 0; m < 4; ++m) {
#pragma unroll
                    for (int nh = 0; nh < 2; ++nh)
#pragma unroll
                        for (int n = 0; n < 2; ++n)
#pragma unroll
                            for (int r2 = 0; r2 < 4; ++r2) {
                                float v = acc[mh * 4 + m][nh * 2 + n][r2];
                                if (BIAS) v += bshift[nh][n];
                                if (GELU) v = gelu_f(v);
                                slab[(q * 4 + r2) * 72 + nh * 32 + n * 16 + l16] = f2b(v);
                            }
#pragma unroll
                    for (int h = 0; h < 2; ++h) {
                        const int lr = h * 8 + (lane >> 3);
                        const int grow = tileM + wm + mh * 64 + m * 16 + lr;
                        const int gcol = tileN + wn + (lane & 7) * 8;
                        uint4 pk = *(const uint4*)&slab[lr * 72 + (lane & 7) * 8];
                        if (RES != 0) {
                            unsigned short* ps = (unsigned short*)&pk;
#pragma unroll
                            for (int j = 0; j < 8; ++j) {
                                float v = b2f(ps[j]);
                                if (RES == 1) v += ((const float*)resid)[(size_t)grow * N + gcol + j];
                                if (RES == 2) v += b2f(((const unsigned short*)resid)[(size_t)grow * N + gcol + j]);
                                ps[j] = f2b(v);
                            }
                        }
                        *(uint4*)&co[(size_t)grow * N + gcol] = pk;
                    }
                }
        } else {
            // f32 out: 16 x 68 f32 slab; waves 0-6 in As[1], wave 7 in Bs[1]
            float* slabf = (w == 7) ? (float*)&Bs[1][0]
                                    : (float*)&As[1][0] + (size_t)w * 1088;
            float* co = (float*)Cout;
#pragma unroll
            for (int mh = 0; mh < 2; ++mh)
#pragma unroll
                for (int m = 0; m < 4; ++m) {
#pragma unroll
                    for (int nh = 0; nh < 2; ++nh)
#pragma unroll
                        for (int n = 0; n < 2; ++n)
#pragma unroll
                            for (int r2 = 0; r2 < 4; ++r2) {
                                float v = acc[mh * 4 + m][nh * 2 + n][r2];
                                if (BIAS) v += bshift[nh][n];
                                if (GELU) v = gelu_f(v);
                                slabf[(q * 4 + r2) * 68 + nh * 32 + n * 16 + l16] = v;
                            }
#pragma unroll
                    for (int i4 = 0; i4 < 4; ++i4) {
                        const int lr = i4 * 4 + (lane >> 4);
                        const int grow = tileM + wm + mh * 64 + m * 16 + lr;
                        const int gcol = tileN + wn + (lane & 15) * 4;
                        f32x4 vv = *(const f32x4*)&slabf[lr * 68 + (lane & 15) * 4];
                        if (RES == 1) {
                            const float4 r4 = *(const float4*)&((const float*)resid)[(size_t)grow * N + gcol];
                            vv[0] += r4.x; vv[1] += r4.y; vv[2] += r4.z; vv[3] += r4.w;
                        }
                        if (RES == 2) {
                            const ushort4 r4 = *(const ushort4*)&((const unsigned short*)resid)[(size_t)grow * N + gcol];
                            vv[0] += b2f(r4.x); vv[1] += b2f(r4.y); vv[2] += b2f(r4.z); vv[3] += b2f(r4.w);
                        }
                        *(f32x4*)&co[(size_t)grow * N + gcol] = vv;
                    }
                }
        }

        if (hasNext) {
            // drain epilogue stores/loads; keep the 4 staged loads (B_Q1,A_P1
            // of next k0) in flight -> K-loop vmcnt arithmetic stays exact.
            asm volatile("s_waitcnt vmcnt(4)" ::: "memory");
            __syncthreads();   // slab reads done before next ph0 DMA hits buf1
        }
    }
}

// ---------------- Attention: MFMA scores + in-register top-16 + softmax ----------------
__global__ __launch_bounds__(256) void attn_topk(const unsigned short* __restrict__ qk,
                                                 unsigned short* __restrict__ aout)
{
    const int bh = blockIdx.x;
    const int b = bh / NHEAD, h = bh % NHEAD;
    __shared__ __align__(16) unsigned short Qs[208 * 64];
    __shared__ __align__(16) unsigned short Ks[208 * 64];
    const int tid = threadIdx.x;

    for (int i = tid; i < 208 * 8; i += 256) {
        int row = i >> 3, c = i & 7;
        uint4 vq = make_uint4(0, 0, 0, 0), vk = vq;
        if (row < SEQ) {
            const uint4* gp = (const uint4*)(qk + ((size_t)(b * SEQ + row) * 1536 + h * 64));
            vq = gp[c];        // q half
            vk = gp[c + 96];   // k half: +768 shorts = +96 uint4
        }
        int slot = c ^ (row & 7);
        *(uint4*)&Qs[row * 64 + slot * 8] = vq;
        *(uint4*)&Ks[row * 64 + slot * 8] = vk;
    }
    __syncthreads();

    const int w = tid >> 6, lane = tid & 63;
    const int q = lane >> 4, l16 = lane & 15;

    for (int tn = w; tn < 13; tn += 4) {
        const int nrow = tn * 16 + l16;
        const int nsw = nrow & 7;
        bf16x8 bq0 = *(const bf16x8*)&Qs[nrow * 64 + ((0 * 4 + q) ^ nsw) * 8];
        bf16x8 bq1 = *(const bf16x8*)&Qs[nrow * 64 + ((1 * 4 + q) ^ nsw) * 8];

        float t[TOPK];
#pragma unroll
        for (int j = 0; j < TOPK; ++j) t[j] = NEGBIG;

        for (int tm = 0; tm < 12; ++tm) {
            const int mrow = tm * 16 + l16;
            const int msw = mrow & 7;
            bf16x8 ak0 = *(const bf16x8*)&Ks[mrow * 64 + ((0 * 4 + q) ^ msw) * 8];
            bf16x8 ak1 = *(const bf16x8*)&Ks[mrow * 64 + ((1 * 4 + q) ^ msw) * 8];
            f32x4 acc = (f32x4){0.f, 0.f, 0.f, 0.f};
            acc = __builtin_amdgcn_mfma_f32_16x16x32_bf16(ak0, bq0, acc, 0, 0, 0);
            acc = __builtin_amdgcn_mfma_f32_16x16x32_bf16(ak1, bq1, acc, 0, 0, 0);
#pragma unroll
            for (int r = 0; r < 4; ++r) {
                float v = acc[r];
#pragma unroll
                for (int j = 0; j < TOPK; ++j) {
                    float mx = fmaxf(t[j], v);
                    v = fminf(t[j], v);
                    t[j] = mx;
                }
            }
        }
        {   // m-tile 12: m = 192 + q*4 + r valid only for q==0
            const int mrow = 12 * 16 + l16;
            const int msw = mrow & 7;
            bf16x8 ak0 = *(const bf16x8*)&Ks[mrow * 64 + ((0 * 4 + q) ^ msw) * 8];
            bf16x8 ak1 = *(const bf16x8*)&Ks[mrow * 64 + ((1 * 4 + q) ^ msw) * 8];
            f32x4 acc = (f32x4){0.f, 0.f, 0.f, 0.f};
            acc = __builtin_amdgcn_mfma_f32_16x16x32_bf16(ak0, bq0, acc, 0, 0, 0);
            acc = __builtin_amdgcn_mfma_f32_16x16x32_bf16(ak1, bq1, acc, 0, 0, 0);
#pragma unroll
            for (int r = 0; r < 4; ++r) {
                float v = (q == 0) ? acc[r] : NEGBIG;
#pragma unroll
                for (int j = 0; j < TOPK; ++j) {
                    float mx = fmaxf(t[j], v);
                    v = fminf(t[j], v);
                    t[j] = mx;
                }
            }
        }

#pragma unroll
        for (int stage = 0; stage < 2; ++stage) {
            const int xm = 16 << stage;
            float bl[TOPK], c[TOPK];
#pragma unroll
            for (int j = 0; j < TOPK; ++j) bl[j] = __shfl_xor(t[j], xm, 64);
#pragma unroll
            for (int j = 0; j < TOPK; ++j) c[j] = fmaxf(t[j], bl[TOPK - 1 - j]);
#pragma unroll
            for (int s = 8; s >= 1; s >>= 1) {
#pragma unroll
                for (int i = 0; i < TOPK; ++i) {
                    if ((i & s) == 0) {
                        float mx = fmaxf(c[i], c[i + s]);
                        c[i + s] = fminf(c[i], c[i + s]);
                        c[i] = mx;
                    }
                }
            }
#pragma unroll
            for (int j = 0; j < TOPK; ++j) t[j] = c[j];
        }

        if (q == 0 && nrow < SEQ) {
            float e[TOPK], sum = 0.f;
#pragma unroll
            for (int j = 0; j < TOPK; ++j) { e[j] = __expf((t[j] - t[0]) * SCALE_F); sum += e[j]; }
            float inv = 1.0f / sum;
            unsigned int pk[8];
#pragma unroll
            for (int jj = 0; jj < 8; ++jj)
                pk[jj] = (unsigned int)f2b(e[2 * jj] * inv) |
                         ((unsigned int)f2b(e[2 * jj + 1] * inv) << 16);
            unsigned short* dst = aout + ((size_t)(b * SEQ + nrow)) * (NHEAD * TOPK) + h * TOPK;
            ((uint4*)dst)[0] = make_uint4(pk[0], pk[1], pk[2], pk[3]);
            ((uint4*)dst)[1] = make_uint4(pk[4], pk[5], pk[6], pk[7]);
        }
    }
}

// ---------------- Launch ----------------
extern "C" void kernel_launch(void* const* d_in, const int* in_sizes, int n_in,
                              void* d_out, int out_size, void* d_ws, size_t ws_size,
                              hipStream_t stream)
{
    const float* x    = (const float*)d_in[0];
    const float* g1   = (const float*)d_in[1];
    const float* bb1  = (const float*)d_in[2];
    const float* qkw  = (const float*)d_in[3];
    const float* pw   = (const float*)d_in[4];
    const float* pb   = (const float*)d_in[5];
    const float* g2   = (const float*)d_in[6];
    const float* bb2  = (const float*)d_in[7];
    const float* f1w  = (const float*)d_in[8];
    const float* f1b  = (const float*)d_in[9];
    const float* f2w  = (const float*)d_in[10];
    const float* f2bp = (const float*)d_in[11];
    float* out = (float*)d_out;

    // layout: hbuf | weights(wqk,wp,wf1,wf2) | av | qk/gg | x1b
    char* ws = (char*)d_ws;
    const size_t SZ_H   = (size_t)MROWS * CH * 2;              // 19,267,584
    const size_t N_WQK  = (size_t)2 * CH * CH;
    const size_t N_WP   = (size_t)CH * (NHEAD * TOPK);
    const size_t N_WF   = (size_t)HID * CH;
    const size_t SZ_W   = (N_WQK + N_WP + 2 * N_WF) * 2;       // 12,091,392
    const size_t SZ_A   = (size_t)MROWS * (NHEAD * TOPK) * 2;  //  4,816,896
    const size_t SZ_QK  = (size_t)MROWS * 2 * CH * 2;          // 38,535,168
    const size_t SZ_GGF = (size_t)MROWS * HID * 2;             // 77,070,336

    unsigned short* hbuf = (unsigned short*)(ws);
    unsigned short* wqk  = (unsigned short*)(ws + SZ_H);
    unsigned short* wp   = wqk + N_WQK;
    unsigned short* wf1  = wp  + N_WP;
    unsigned short* wf2  = wf1 + N_WF;
    unsigned short* av   = (unsigned short*)(ws + SZ_H + SZ_W);
    unsigned short* qk   = (unsigned short*)(ws + SZ_H + SZ_W + SZ_A);
    unsigned short* gg   = qk;   // overlays qk (dead by MLP time)

    const size_t base = SZ_H + SZ_W + SZ_A;
    const bool fullMLP = ws_size >= base + SZ_GGF + SZ_H;      // 132.5 MB: full-M + bf16 x1
    const bool bx1     = fullMLP || ws_size >= base + SZ_QK + SZ_H;  // 94 MB: halves + bf16 x1
    unsigned short* x1b = (unsigned short*)(ws + base + (fullMLP ? SZ_GGF : SZ_QK));
    float* x1 = out;   // f32 fallback residual lives in d_out

    // 0) all weights f32 -> bf16, one dispatch
    {
        int total4 = (int)((N_WQK + N_WP + 2 * N_WF) / 4);
        f2b4_k<<<(total4 + 255) / 256, 256, 0, stream>>>(
            qkw, wqk, (int)N_WQK, pw, wp, (int)N_WP,
            f1w, wf1, (int)N_WF, f2w, wf2, (int)N_WF);
    }

    // 1) LN1: x(f32) -> h (bf16)
    ln_k<true><<<MROWS, 256, 0, stream>>>(x, g1, bb1, hbuf);
    // 2) qk = h @ qk_w^T   [12544 x 1536], K=768   (persistent: 294 tiles on 256 blocks)
    gemm8p<CH, false, 0, false, false><<<256, 512, 0, stream>>>(
        hbuf, wqk, nullptr, nullptr, qk, MROWS, 2 * CH);
    // 3) attention -> top16 softmax weights [12544 x 192] bf16
    attn_topk<<<BATCH * NHEAD, 256, 0, stream>>>(qk, av);

    if (bx1) {
        // 4) x1b = bf16(x + a @ attn_proj_w^T + b)   (64x128: grid 6x196)
        gemm_bt<64, 128, true, 1, false, false><<<dim3(6, 196), 256, 0, stream>>>(
            av, wp, pb, x, x1b, MROWS, CH, NHEAD * TOPK);
        // 5) LN2: x1b (bf16) -> h2
        ln_k<false><<<MROWS, 256, 0, stream>>>(x1b, g2, bb2, hbuf);
        if (fullMLP) {
            // fc1: [12544 x 3072], K=768  (588 tiles on 256 blocks)
            gemm8p<CH, true, 0, true, false><<<256, 512, 0, stream>>>(
                hbuf, wf1, f1b, nullptr, gg, MROWS, HID);
            // fc2: [12544 x 768], K=3072 (147 tiles on 147 blocks)
            gemm8p<HID, true, 2, false, true><<<147, 512, 0, stream>>>(
                gg, wf2, f2bp, x1b, out, MROWS, CH);
        } else {
            for (int half = 0; half < 2; ++half) {
                const size_t ro = (size_t)half * MHALF;
                gemm_bt<128, 128, true, 0, true, false><<<dim3(24, 49), 256, 0, stream>>>(
                    hbuf + ro * CH, wf1, f1b, nullptr, gg, MHALF, HID, CH);
                gemm_bt<64, 256, true, 2, false, true><<<dim3(3, 98), 256, 0, stream>>>(
                    gg, wf2, f2bp, x1b + ro * CH, out + ro * CH, MHALF, CH, HID);
            }
        }
    } else {
        // conservative fallback: f32 x1 in d_out, halved MLP (74.7 MB ws)
        gemm_bt<64, 128, true, 1, false, true><<<dim3(6, 196), 256, 0, stream>>>(
            av, wp, pb, x, x1, MROWS, CH, NHEAD * TOPK);
        ln_k<true><<<MROWS, 256, 0, stream>>>(x1, g2, bb2, hbuf);
        for (int half = 0; half < 2; ++half) {
            const size_t ro = (size_t)half * MHALF;
            gemm_bt<128, 128, true, 0, true, false><<<dim3(24, 49), 256, 0, stream>>>(
                hbuf + ro * CH, wf1, f1b, nullptr, gg, MHALF, HID, CH);
            gemm_bt<64, 256, true, 1, false, true><<<dim3(3, 98), 256, 0, stream>>>(
                gg, wf2, f2bp, x1 + ro * CH, out + ro * CH, MHALF, CH, HID);
        }
    }
}